// Round 16
// baseline (192.937 us; speedup 1.0000x reference)
//
#include <hip/hip_runtime.h>
#include <hip/hip_bf16.h>
#include <math.h>

#define M_TOT   16384      // B*N = 4*4096
#define F_DIM   768
#define C_DIM   64
#define P_DIM   8192
#define EPSN    1e-12f
#define NEG_BIG (-3.402823466e38f)
#define NCH     16
#define PCH     (P_DIM / NCH)   // 512
#define GRP     32
#define NGRP    (P_DIM / GRP)   // 256
#define MARG    1e-2f           // >= 2 * 4e-3 hard bf16x1 screen error bound

typedef __attribute__((ext_vector_type(8))) short bf16x8;
typedef __attribute__((ext_vector_type(4))) float f32x4;
typedef unsigned short ushort_t;
typedef const __attribute__((address_space(1))) void* gas1_t;
typedef __attribute__((address_space(3))) void* las3_t;

__device__ inline ushort_t bf16hi(float v) {
    __hip_bfloat16 hb = __float2bfloat16(v);
    return *reinterpret_cast<ushort_t*>(&hb);
}

// ---------------- Kernel A: cn = l2norm(codebook) + bf16 round ----------------
__global__ void k_norm_cb(const float* __restrict__ cb, float* __restrict__ cn,
                          ushort_t* __restrict__ ch) {
    int wv = threadIdx.x >> 6, lane = threadIdx.x & 63;
    int row = blockIdx.x * 4 + wv;
    float v = cb[(size_t)row * C_DIM + lane];
    float s = v * v;
    #pragma unroll
    for (int o = 32; o; o >>= 1) s += __shfl_xor(s, o, 64);
    float inv = 1.0f / fmaxf(sqrtf(s), EPSN);
    float nv = v * inv;
    size_t i = (size_t)row * C_DIM + lane;
    cn[i] = nv;
    ch[i] = bf16hi(nv);
}

// ---------------- Kernel A2: w_outT[c][f] = w_out[f][c] ----------------
__global__ void k_transpose_wout(const float* __restrict__ w_out, float* __restrict__ wT) {
    int i = blockIdx.x * 256 + threadIdx.x;   // 49152 total
    int f = i >> 6, c = i & 63;
    wT[(size_t)c * F_DIM + f] = w_out[i];
}

// ---------------- Kernel B: zn = l2norm(z @ w_in^T), tiled fp32 GEMM ----------
// PBM=64, 4 rows/thread: per kq = 64 fmaf (128 issue cyc) vs 4 z-loads (<=4
// distinct addrs/wave-inst, broadcast within 16-lane groups) + 4 ds_reads ->
// ~85% VALU issue fraction, 2x FMA per staged w byte and per barrier. w staged
// via global_load_lds dbuf, pre-swizzled source. FMA chain per output is
// k-ascending x,y,z,w -- BITWISE identical zn to previous rounds.
#define PBM 64
#define PKC 64
__global__ __launch_bounds__(256)
void k_proj(const float* __restrict__ z, const float* __restrict__ w_in,
            float* __restrict__ zn, ushort_t* __restrict__ zh) {
    __shared__ float lw[2][C_DIM * PKC];   // 2 x 16 KB  [c][slot*4]

    const int t  = threadIdx.x;
    const int m0 = blockIdx.x * PBM;
    const int r0 = (t >> 4) * 4;        // rows r0..r0+3  (t>>4 in 0..15)
    const int c0 = (t & 15) * 4;        // cols c0..c0+3
    const int wswz = t & 15;            // == ((c0+cj)>>2)&15 for cj<4

    const float* zrow[4];
    #pragma unroll
    for (int ri = 0; ri < 4; ++ri)
        zrow[ri] = z + (size_t)(m0 + r0 + ri) * F_DIM;

    float acc[4][4];
    #pragma unroll
    for (int i = 0; i < 4; ++i)
        #pragma unroll
        for (int j = 0; j < 4; ++j) acc[i][j] = 0.0f;

    // stage w chunk 0 into buffer 0 (1024 float4 over 256 thr = 4 each)
    #pragma unroll
    for (int i = 0; i < 4; ++i) {
        int f4 = i * 256 + t; int c = f4 >> 4, s4 = f4 & 15;
        __builtin_amdgcn_global_load_lds(
            (gas1_t)(w_in + (size_t)c * F_DIM + (s4 ^ ((c >> 2) & 15)) * 4),
            (las3_t)(&lw[0][f4 * 4]), 16, 0, 0);
    }
    __syncthreads();

    int cur = 0;
    for (int k0 = 0; k0 < F_DIM; k0 += PKC) {       // 12 chunks
        if (k0 + PKC < F_DIM) {                     // issue next-chunk DMA first
            int nxt = cur ^ 1;
            #pragma unroll
            for (int i = 0; i < 4; ++i) {
                int f4 = i * 256 + t; int c = f4 >> 4, s4 = f4 & 15;
                __builtin_amdgcn_global_load_lds(
                    (gas1_t)(w_in + (size_t)c * F_DIM + k0 + PKC
                             + (s4 ^ ((c >> 2) & 15)) * 4),
                    (las3_t)(&lw[nxt][f4 * 4]), 16, 0, 0);
            }
        }

        const float* lwb = lw[cur];
        #pragma unroll
        for (int kq = 0; kq < 16; ++kq) {
            float4 zf[4], wf[4];
            int wo = (kq ^ wswz) * 4;
            #pragma unroll
            for (int ri = 0; ri < 4; ++ri)
                zf[ri] = *(const float4*)(zrow[ri] + k0 + kq * 4);
            #pragma unroll
            for (int cj = 0; cj < 4; ++cj)
                wf[cj] = *(const float4*)(lwb + (c0 + cj) * PKC + wo);
            #pragma unroll
            for (int ri = 0; ri < 4; ++ri)
                #pragma unroll
                for (int cj = 0; cj < 4; ++cj) {
                    acc[ri][cj] = fmaf(zf[ri].x, wf[cj].x, acc[ri][cj]);
                    acc[ri][cj] = fmaf(zf[ri].y, wf[cj].y, acc[ri][cj]);
                    acc[ri][cj] = fmaf(zf[ri].z, wf[cj].z, acc[ri][cj]);
                    acc[ri][cj] = fmaf(zf[ri].w, wf[cj].w, acc[ri][cj]);
                }
        }
        __syncthreads();    // vmcnt(0)+barrier: next w chunk landed, cur free
        cur ^= 1;
    }

    // ---- epilogue: row-norm (16-lane group holds one row's 64 c) ----
    #pragma unroll
    for (int ri = 0; ri < 4; ++ri) {
        float s = acc[ri][0] * acc[ri][0] + acc[ri][1] * acc[ri][1]
                + acc[ri][2] * acc[ri][2] + acc[ri][3] * acc[ri][3];
        #pragma unroll
        for (int o = 1; o < 16; o <<= 1) s += __shfl_xor(s, o, 64);
        float inv = 1.0f / fmaxf(sqrtf(s), EPSN);
        float4 v;
        v.x = acc[ri][0] * inv; v.y = acc[ri][1] * inv;
        v.z = acc[ri][2] * inv; v.w = acc[ri][3] * inv;
        size_t base = (size_t)(m0 + r0 + ri) * C_DIM + c0;
        *(float4*)(zn + base) = v;
        ushort4 hv = {bf16hi(v.x), bf16hi(v.y), bf16hi(v.z), bf16hi(v.w)};
        *(ushort4*)(zh + base) = hv;
    }
}

// ---------------- Kernel C: bf16x1 MFMA screen -> per-32-code group maxima ----------
// r11's proven version: plain per-tile loads, NCH=16, 4 waves/EU. Screen err
// <= 4e-3 hard; k_pick rescans exact fp32 with MARG = 1e-2 >= 2*err.
__global__ __launch_bounds__(256, 4)
void k_simmax(const ushort_t* __restrict__ zh, const ushort_t* __restrict__ ch,
              float* __restrict__ gmax) {
    int wv = threadIdx.x >> 6, l = threadIdx.x & 63;
    int m0 = (blockIdx.x * 4 + wv) * 64;
    int p0 = blockIdx.y * PCH;
    int col = l & 15, quad = l >> 4;
    int kb = quad * 8;

    bf16x8 bh[4][2];
    #pragma unroll
    for (int mt = 0; mt < 4; ++mt) {
        const ushort_t* zr = zh + (size_t)(m0 + mt * 16 + col) * C_DIM + kb;
        #pragma unroll
        for (int ks = 0; ks < 2; ++ks)
            bh[mt][ks] = *(const bf16x8*)(zr + ks * 32);
    }

    for (int g = 0; g < PCH / GRP; ++g) {           // 16 groups of 32 p
        float gm[4];
        #pragma unroll
        for (int mt = 0; mt < 4; ++mt) gm[mt] = NEG_BIG;

        #pragma unroll
        for (int half = 0; half < 2; ++half) {      // 2 16-p tiles per group
            int pt = g * 2 + half;
            size_t prow = (size_t)(p0 + pt * 16 + col) * C_DIM + kb;
            bf16x8 ah0 = *(const bf16x8*)(ch + prow);
            bf16x8 ah1 = *(const bf16x8*)(ch + prow + 32);
            #pragma unroll
            for (int mt = 0; mt < 4; ++mt) {
                f32x4 acc = {0.f, 0.f, 0.f, 0.f};
                acc = __builtin_amdgcn_mfma_f32_16x16x32_bf16(ah0, bh[mt][0], acc, 0, 0, 0);
                acc = __builtin_amdgcn_mfma_f32_16x16x32_bf16(ah1, bh[mt][1], acc, 0, 0, 0);
                float tm = fmaxf(fmaxf(acc[0], acc[1]), fmaxf(acc[2], acc[3]));
                gm[mt] = fmaxf(gm[mt], tm);
            }
        }
        #pragma unroll
        for (int mt = 0; mt < 4; ++mt) {
            float v = gm[mt];
            v = fmaxf(v, __shfl_xor(v, 16, 64));
            v = fmaxf(v, __shfl_xor(v, 32, 64));
            if (quad == 0)
                gmax[(size_t)(blockIdx.y * (PCH / GRP) + g) * M_TOT + m0 + mt * 16 + col] = v;
        }
    }
}

// ---------------- Kernel C2: per-row pick + fused loss partial ----------
__global__ __launch_bounds__(256)
void k_pick(const float* __restrict__ gmax, const float* __restrict__ zn,
            const float* __restrict__ cn, int* __restrict__ idx_i,
            float* __restrict__ idx_f, float* __restrict__ lossp) {
    int wv = threadIdx.x >> 6, l = threadIdx.x & 63;
    int m = blockIdx.x * 4 + wv;            // one wave per row

    float gv[4];
    #pragma unroll
    for (int b = 0; b < 4; ++b)
        gv[b] = gmax[(size_t)(b * 64 + l) * M_TOT + m];
    float rm = fmaxf(fmaxf(gv[0], gv[1]), fmaxf(gv[2], gv[3]));
    #pragma unroll
    for (int o = 32; o; o >>= 1) rm = fmaxf(rm, __shfl_xor(rm, o, 64));
    float thr = rm - MARG;

    // zn row: lane holds half the row (half = l>>5)
    float zr[32];
    {
        const float4* zp = (const float4*)(zn + (size_t)m * C_DIM + (l >> 5) * 32);
        #pragma unroll
        for (int q = 0; q < 8; ++q) {
            float4 v = zp[q];
            zr[4 * q] = v.x; zr[4 * q + 1] = v.y;
            zr[4 * q + 2] = v.z; zr[4 * q + 3] = v.w;
        }
    }

    float bv = NEG_BIG; int bp = P_DIM;
    #pragma unroll
    for (int b = 0; b < 4; ++b) {           // ascending batches -> ascending groups
        unsigned long long mask = __ballot(gv[b] >= thr);
        while (mask) {
            int j = __ffsll((unsigned long long)mask) - 1;
            mask &= mask - 1;               // ascending j within batch
            int g = b * 64 + j;
            int p = g * GRP + (l & 31);
            const float4* cp = (const float4*)(cn + (size_t)p * C_DIM + (l >> 5) * 32);
            float a0 = 0.f, a1 = 0.f, a2 = 0.f, a3 = 0.f;
            #pragma unroll
            for (int q = 0; q < 8; ++q) {
                float4 w = cp[q];
                a0 = fmaf(w.x, zr[4 * q + 0], a0);
                a1 = fmaf(w.y, zr[4 * q + 1], a1);
                a2 = fmaf(w.z, zr[4 * q + 2], a2);
                a3 = fmaf(w.w, zr[4 * q + 3], a3);
            }
            float s = (a0 + a1) + (a2 + a3);
            s += __shfl_xor(s, 32, 64);     // combine halves: full dot in both lanes
            if (s > bv || (s == bv && p < bp)) { bv = s; bp = p; }
        }
    }
    #pragma unroll
    for (int o = 32; o; o >>= 1) {
        float ov = __shfl_xor(bv, o, 64);
        int   op = __shfl_xor(bp, o, 64);
        if (ov > bv || (ov == bv && op < bp)) { bv = ov; bp = op; }
    }
    if (l == 0) { idx_i[m] = bp; idx_f[m] = (float)bp; }

    // fused loss partial: sum (zn - cn[bp])^2 over the row (bp wave-uniform)
    {
        const float4* cp = (const float4*)(cn + (size_t)bp * C_DIM + (l >> 5) * 32);
        float d2 = 0.f;
        #pragma unroll
        for (int q = 0; q < 8; ++q) {
            float4 w = cp[q];
            float dx = zr[4 * q + 0] - w.x; d2 = fmaf(dx, dx, d2);
            float dy = zr[4 * q + 1] - w.y; d2 = fmaf(dy, dy, d2);
            float dz = zr[4 * q + 2] - w.z; d2 = fmaf(dz, dz, d2);
            float dw = zr[4 * q + 3] - w.w; d2 = fmaf(dw, dw, d2);
        }
        d2 += __shfl_xor(d2, 32, 64);
        if (l == 0) lossp[m] = d2;
    }
}

// ---------------- Kernel D: out = codes @ w_outT, 4 independent FMA chains ----
#define D_ROWS 128
__global__ void k_out(const int* __restrict__ idx, const float* __restrict__ cn,
                      const float* __restrict__ wT, float* __restrict__ out) {
    int wv = threadIdx.x >> 6, lane = threadIdx.x & 63;
    int f  = blockIdx.y * 64 + lane;
    int m0 = blockIdx.x * D_ROWS + wv * 32;

    float wcol[64];
    #pragma unroll
    for (int c = 0; c < 64; ++c) wcol[c] = wT[(size_t)c * F_DIM + f];

    #pragma unroll 4
    for (int r = 0; r < 32; ++r) {
        int m = __builtin_amdgcn_readfirstlane(m0 + r);
        const float4* cp = (const float4*)(cn + (size_t)idx[m] * C_DIM);
        float a0 = 0.f, a1 = 0.f, a2 = 0.f, a3 = 0.f;
        #pragma unroll
        for (int j = 0; j < 16; ++j) {
            float4 cv = cp[j];
            a0 = fmaf(cv.x, wcol[4 * j + 0], a0);
            a1 = fmaf(cv.y, wcol[4 * j + 1], a1);
            a2 = fmaf(cv.z, wcol[4 * j + 2], a2);
            a3 = fmaf(cv.w, wcol[4 * j + 3], a3);
        }
        out[(size_t)m * F_DIM + f] = (a0 + a1) + (a2 + a3);
    }
}

// ---------------- Kernel F: finalize loss (deterministic) ----------------
__global__ void k_loss_final(const float* __restrict__ lossp, float* __restrict__ loss_out) {
    __shared__ float sh[256];
    float s = 0.f;
    for (int i = threadIdx.x; i < M_TOT; i += 256) s += lossp[i];
    sh[threadIdx.x] = s;
    __syncthreads();
    for (int o = 128; o; o >>= 1) {
        if (threadIdx.x < o) sh[threadIdx.x] += sh[threadIdx.x + o];
        __syncthreads();
    }
    if (threadIdx.x == 0)
        loss_out[0] = 1.25f * sh[0] / (float)(M_TOT * C_DIM);
}

extern "C" void kernel_launch(void* const* d_in, const int* in_sizes, int n_in,
                              void* d_out, int out_size, void* d_ws, size_t ws_size,
                              hipStream_t stream) {
    const float* z     = (const float*)d_in[0];
    const float* w_in  = (const float*)d_in[1];
    const float* w_out = (const float*)d_in[2];
    const float* cb    = (const float*)d_in[3];

    float* out    = (float*)d_out;
    float* lossO  = out + (size_t)M_TOT * F_DIM;
    float* idxO   = lossO + 1;
    // gmax (16.8 MB) lives in the d_out 'out' region: written by k_simmax, read
    // by k_pick, then fully overwritten by k_out afterwards (stream-ordered).
    float* gmax   = out;

    float* ws    = (float*)d_ws;                          // total ~9.4 MB
    float* cn    = ws;                                    // 524288 f   (2 MB)
    float* zn    = cn + (size_t)P_DIM * C_DIM;            // 1048576 f  (4 MB)
    float* wT    = zn + (size_t)M_TOT * C_DIM;            // 49152 f
    float* lossp = wT + (size_t)C_DIM * F_DIM;            // 16384 f
    int*   idxi  = (int*)(lossp + M_TOT);                 // 16384 i
    ushort_t* zh = (ushort_t*)(idxi + M_TOT);             // 1048576 us (2 MB)
    ushort_t* ch = zh + (size_t)M_TOT * C_DIM;            // 524288 us  (1 MB)

    k_norm_cb<<<P_DIM / 4, 256, 0, stream>>>(cb, cn, ch);
    k_transpose_wout<<<(C_DIM * F_DIM) / 256, 256, 0, stream>>>(w_out, wT);
    k_proj<<<M_TOT / PBM, 256, 0, stream>>>(z, w_in, zn, zh);

    dim3 gC(M_TOT / 256, NCH);
    k_simmax<<<gC, 256, 0, stream>>>(zh, ch, gmax);
    k_pick<<<M_TOT / 4, 256, 0, stream>>>(gmax, zn, cn, idxi, idxO, lossp);

    dim3 gD(M_TOT / D_ROWS, F_DIM / 64);
    k_out<<<gD, 256, 0, stream>>>(idxi, cn, wT, out);

    k_loss_final<<<1, 256, 0, stream>>>(lossp, lossO);
}

// Round 17
// 186.248 us; speedup vs baseline: 1.0359x; 1.0359x over previous
//
#include <hip/hip_runtime.h>
#include <hip/hip_bf16.h>
#include <math.h>

#define M_TOT   16384      // B*N = 4*4096
#define F_DIM   768
#define C_DIM   64
#define P_DIM   8192
#define EPSN    1e-12f
#define NEG_BIG (-3.402823466e38f)
#define NCH     16
#define PCH     (P_DIM / NCH)   // 512
#define GRP     32
#define NGRP    (P_DIM / GRP)   // 256
#define MARG    1e-2f           // >= 2 * 4e-3 hard bf16x1 screen error bound

typedef __attribute__((ext_vector_type(8))) short bf16x8;
typedef __attribute__((ext_vector_type(4))) float f32x4;
typedef unsigned short ushort_t;
typedef const __attribute__((address_space(1))) void* gas1_t;
typedef __attribute__((address_space(3))) void* las3_t;

__device__ inline ushort_t bf16hi(float v) {
    __hip_bfloat16 hb = __float2bfloat16(v);
    return *reinterpret_cast<ushort_t*>(&hb);
}

// ---------------- Kernel A (merged): codebook norm + w_out transpose ----------
// blocks [0, P_DIM/4): cn = l2norm(codebook) rows + bf16 round.
// blocks [P_DIM/4, P_DIM/4 + 192): wT[c][f] = w_out[f][c].
__global__ void k_prep(const float* __restrict__ cb, float* __restrict__ cn,
                       ushort_t* __restrict__ ch, const float* __restrict__ w_out,
                       float* __restrict__ wT) {
    int bx = blockIdx.x;
    if (bx < P_DIM / 4) {
        int wv = threadIdx.x >> 6, lane = threadIdx.x & 63;
        int row = bx * 4 + wv;
        float v = cb[(size_t)row * C_DIM + lane];
        float s = v * v;
        #pragma unroll
        for (int o = 32; o; o >>= 1) s += __shfl_xor(s, o, 64);
        float inv = 1.0f / fmaxf(sqrtf(s), EPSN);
        float nv = v * inv;
        size_t i = (size_t)row * C_DIM + lane;
        cn[i] = nv;
        ch[i] = bf16hi(nv);
    } else {
        int i = (bx - P_DIM / 4) * 256 + threadIdx.x;   // 49152 total
        int f = i >> 6, c = i & 63;
        wT[(size_t)c * F_DIM + f] = w_out[i];
    }
}

// ---------------- Kernel B: zn = l2norm(z @ w_in^T), tiled fp32 GEMM ----------
// r15's proven version (best total 188.5). 256 threads (4 waves), 32m x 64c
// tile. z DIRECT from global (4-row broadcast per wave inst, L1-resident);
// w staged via global_load_lds double-buffer with pre-swizzled source. Thread
// = 2x4 acc block. FMA chain per output is k-ascending x,y,z,w -- BITWISE
// identical zn to all passing rounds (idx exactness depends on this).
#define PBM 32
#define PKC 64
__global__ __launch_bounds__(256)
void k_proj(const float* __restrict__ z, const float* __restrict__ w_in,
            float* __restrict__ zn, ushort_t* __restrict__ zh) {
    __shared__ float lw[2][C_DIM * PKC];   // 2 x 16 KB  [c][slot*4]

    const int t  = threadIdx.x;
    const int m0 = blockIdx.x * PBM;
    const int r0 = (t >> 4) * 2;        // rows r0..r0+1  (t>>4 in 0..15)
    const int c0 = (t & 15) * 4;        // cols c0..c0+3
    const int wswz = t & 15;            // == ((c0+cj)>>2)&15 for cj<4

    const float* zrow[2];
    #pragma unroll
    for (int ri = 0; ri < 2; ++ri)
        zrow[ri] = z + (size_t)(m0 + r0 + ri) * F_DIM;

    float acc[2][4];
    #pragma unroll
    for (int i = 0; i < 2; ++i)
        #pragma unroll
        for (int j = 0; j < 4; ++j) acc[i][j] = 0.0f;

    // stage w chunk 0 into buffer 0 (1024 float4 over 256 thr = 4 each)
    #pragma unroll
    for (int i = 0; i < 4; ++i) {
        int f4 = i * 256 + t; int c = f4 >> 4, s4 = f4 & 15;
        __builtin_amdgcn_global_load_lds(
            (gas1_t)(w_in + (size_t)c * F_DIM + (s4 ^ ((c >> 2) & 15)) * 4),
            (las3_t)(&lw[0][f4 * 4]), 16, 0, 0);
    }
    __syncthreads();

    int cur = 0;
    for (int k0 = 0; k0 < F_DIM; k0 += PKC) {       // 12 chunks
        if (k0 + PKC < F_DIM) {                     // issue next-chunk DMA first
            int nxt = cur ^ 1;
            #pragma unroll
            for (int i = 0; i < 4; ++i) {
                int f4 = i * 256 + t; int c = f4 >> 4, s4 = f4 & 15;
                __builtin_amdgcn_global_load_lds(
                    (gas1_t)(w_in + (size_t)c * F_DIM + k0 + PKC
                             + (s4 ^ ((c >> 2) & 15)) * 4),
                    (las3_t)(&lw[nxt][f4 * 4]), 16, 0, 0);
            }
        }

        const float* lwb = lw[cur];
        #pragma unroll
        for (int kq = 0; kq < 16; ++kq) {
            float4 zf[2], wf[4];
            int wo = (kq ^ wswz) * 4;
            #pragma unroll
            for (int ri = 0; ri < 2; ++ri)
                zf[ri] = *(const float4*)(zrow[ri] + k0 + kq * 4);
            #pragma unroll
            for (int cj = 0; cj < 4; ++cj)
                wf[cj] = *(const float4*)(lwb + (c0 + cj) * PKC + wo);
            #pragma unroll
            for (int ri = 0; ri < 2; ++ri)
                #pragma unroll
                for (int cj = 0; cj < 4; ++cj) {
                    acc[ri][cj] = fmaf(zf[ri].x, wf[cj].x, acc[ri][cj]);
                    acc[ri][cj] = fmaf(zf[ri].y, wf[cj].y, acc[ri][cj]);
                    acc[ri][cj] = fmaf(zf[ri].z, wf[cj].z, acc[ri][cj]);
                    acc[ri][cj] = fmaf(zf[ri].w, wf[cj].w, acc[ri][cj]);
                }
        }
        __syncthreads();    // vmcnt(0)+barrier: next w chunk landed, cur free
        cur ^= 1;
    }

    // ---- epilogue: row-norm (16-lane group holds one row's 64 c) ----
    #pragma unroll
    for (int ri = 0; ri < 2; ++ri) {
        float s = acc[ri][0] * acc[ri][0] + acc[ri][1] * acc[ri][1]
                + acc[ri][2] * acc[ri][2] + acc[ri][3] * acc[ri][3];
        #pragma unroll
        for (int o = 1; o < 16; o <<= 1) s += __shfl_xor(s, o, 64);
        float inv = 1.0f / fmaxf(sqrtf(s), EPSN);
        float4 v;
        v.x = acc[ri][0] * inv; v.y = acc[ri][1] * inv;
        v.z = acc[ri][2] * inv; v.w = acc[ri][3] * inv;
        size_t base = (size_t)(m0 + r0 + ri) * C_DIM + c0;
        *(float4*)(zn + base) = v;
        ushort4 hv = {bf16hi(v.x), bf16hi(v.y), bf16hi(v.z), bf16hi(v.w)};
        *(ushort4*)(zh + base) = hv;
    }
}

// ---------------- Kernel C: bf16x1 MFMA screen -> per-32-code group maxima ----------
// r11's proven version: plain per-tile loads, NCH=16, 4 waves/EU. Screen err
// <= 4e-3 hard; k_pick rescans exact fp32 with MARG = 1e-2 >= 2*err.
__global__ __launch_bounds__(256, 4)
void k_simmax(const ushort_t* __restrict__ zh, const ushort_t* __restrict__ ch,
              float* __restrict__ gmax) {
    int wv = threadIdx.x >> 6, l = threadIdx.x & 63;
    int m0 = (blockIdx.x * 4 + wv) * 64;
    int p0 = blockIdx.y * PCH;
    int col = l & 15, quad = l >> 4;
    int kb = quad * 8;

    bf16x8 bh[4][2];
    #pragma unroll
    for (int mt = 0; mt < 4; ++mt) {
        const ushort_t* zr = zh + (size_t)(m0 + mt * 16 + col) * C_DIM + kb;
        #pragma unroll
        for (int ks = 0; ks < 2; ++ks)
            bh[mt][ks] = *(const bf16x8*)(zr + ks * 32);
    }

    for (int g = 0; g < PCH / GRP; ++g) {           // 16 groups of 32 p
        float gm[4];
        #pragma unroll
        for (int mt = 0; mt < 4; ++mt) gm[mt] = NEG_BIG;

        #pragma unroll
        for (int half = 0; half < 2; ++half) {      // 2 16-p tiles per group
            int pt = g * 2 + half;
            size_t prow = (size_t)(p0 + pt * 16 + col) * C_DIM + kb;
            bf16x8 ah0 = *(const bf16x8*)(ch + prow);
            bf16x8 ah1 = *(const bf16x8*)(ch + prow + 32);
            #pragma unroll
            for (int mt = 0; mt < 4; ++mt) {
                f32x4 acc = {0.f, 0.f, 0.f, 0.f};
                acc = __builtin_amdgcn_mfma_f32_16x16x32_bf16(ah0, bh[mt][0], acc, 0, 0, 0);
                acc = __builtin_amdgcn_mfma_f32_16x16x32_bf16(ah1, bh[mt][1], acc, 0, 0, 0);
                float tm = fmaxf(fmaxf(acc[0], acc[1]), fmaxf(acc[2], acc[3]));
                gm[mt] = fmaxf(gm[mt], tm);
            }
        }
        #pragma unroll
        for (int mt = 0; mt < 4; ++mt) {
            float v = gm[mt];
            v = fmaxf(v, __shfl_xor(v, 16, 64));
            v = fmaxf(v, __shfl_xor(v, 32, 64));
            if (quad == 0)
                gmax[(size_t)(blockIdx.y * (PCH / GRP) + g) * M_TOT + m0 + mt * 16 + col] = v;
        }
    }
}

// ---------------- Kernel C2: per-row pick + fused loss partial ----------
// One wave per row. Lane l holds groups {l, l+64, l+128, l+192}. Row max via
// shuffle; __ballot flags candidates; wave-parallel exact fp32 rescan (np tie
// rules: groups ascending, strict >, min p). Fused (zn-cn[bp])^2 partial.
__global__ __launch_bounds__(256)
void k_pick(const float* __restrict__ gmax, const float* __restrict__ zn,
            const float* __restrict__ cn, int* __restrict__ idx_i,
            float* __restrict__ idx_f, float* __restrict__ lossp) {
    int wv = threadIdx.x >> 6, l = threadIdx.x & 63;
    int m = blockIdx.x * 4 + wv;            // one wave per row

    float gv[4];
    #pragma unroll
    for (int b = 0; b < 4; ++b)
        gv[b] = gmax[(size_t)(b * 64 + l) * M_TOT + m];
    float rm = fmaxf(fmaxf(gv[0], gv[1]), fmaxf(gv[2], gv[3]));
    #pragma unroll
    for (int o = 32; o; o >>= 1) rm = fmaxf(rm, __shfl_xor(rm, o, 64));
    float thr = rm - MARG;

    // zn row: lane holds half the row (half = l>>5)
    float zr[32];
    {
        const float4* zp = (const float4*)(zn + (size_t)m * C_DIM + (l >> 5) * 32);
        #pragma unroll
        for (int q = 0; q < 8; ++q) {
            float4 v = zp[q];
            zr[4 * q] = v.x; zr[4 * q + 1] = v.y;
            zr[4 * q + 2] = v.z; zr[4 * q + 3] = v.w;
        }
    }

    float bv = NEG_BIG; int bp = P_DIM;
    #pragma unroll
    for (int b = 0; b < 4; ++b) {           // ascending batches -> ascending groups
        unsigned long long mask = __ballot(gv[b] >= thr);
        while (mask) {
            int j = __ffsll((unsigned long long)mask) - 1;
            mask &= mask - 1;               // ascending j within batch
            int g = b * 64 + j;
            int p = g * GRP + (l & 31);
            const float4* cp = (const float4*)(cn + (size_t)p * C_DIM + (l >> 5) * 32);
            float a0 = 0.f, a1 = 0.f, a2 = 0.f, a3 = 0.f;
            #pragma unroll
            for (int q = 0; q < 8; ++q) {
                float4 w = cp[q];
                a0 = fmaf(w.x, zr[4 * q + 0], a0);
                a1 = fmaf(w.y, zr[4 * q + 1], a1);
                a2 = fmaf(w.z, zr[4 * q + 2], a2);
                a3 = fmaf(w.w, zr[4 * q + 3], a3);
            }
            float s = (a0 + a1) + (a2 + a3);
            s += __shfl_xor(s, 32, 64);     // combine halves: full dot in both lanes
            if (s > bv || (s == bv && p < bp)) { bv = s; bp = p; }
        }
    }
    #pragma unroll
    for (int o = 32; o; o >>= 1) {
        float ov = __shfl_xor(bv, o, 64);
        int   op = __shfl_xor(bp, o, 64);
        if (ov > bv || (ov == bv && op < bp)) { bv = ov; bp = op; }
    }
    if (l == 0) { idx_i[m] = bp; idx_f[m] = (float)bp; }

    // fused loss partial: sum (zn - cn[bp])^2 over the row (bp wave-uniform)
    {
        const float4* cp = (const float4*)(cn + (size_t)bp * C_DIM + (l >> 5) * 32);
        float d2 = 0.f;
        #pragma unroll
        for (int q = 0; q < 8; ++q) {
            float4 w = cp[q];
            float dx = zr[4 * q + 0] - w.x; d2 = fmaf(dx, dx, d2);
            float dy = zr[4 * q + 1] - w.y; d2 = fmaf(dy, dy, d2);
            float dz = zr[4 * q + 2] - w.z; d2 = fmaf(dz, dz, d2);
            float dw = zr[4 * q + 3] - w.w; d2 = fmaf(dw, dw, d2);
        }
        d2 += __shfl_xor(d2, 32, 64);
        if (l == 0) lossp[m] = d2;
    }
}

// ---------------- Kernel D: out = codes @ w_outT, 4 independent FMA chains ----
#define D_ROWS 128
__global__ void k_out(const int* __restrict__ idx, const float* __restrict__ cn,
                      const float* __restrict__ wT, float* __restrict__ out) {
    int wv = threadIdx.x >> 6, lane = threadIdx.x & 63;
    int f  = blockIdx.y * 64 + lane;
    int m0 = blockIdx.x * D_ROWS + wv * 32;

    float wcol[64];
    #pragma unroll
    for (int c = 0; c < 64; ++c) wcol[c] = wT[(size_t)c * F_DIM + f];

    #pragma unroll 4
    for (int r = 0; r < 32; ++r) {
        int m = __builtin_amdgcn_readfirstlane(m0 + r);
        const float4* cp = (const float4*)(cn + (size_t)idx[m] * C_DIM);
        float a0 = 0.f, a1 = 0.f, a2 = 0.f, a3 = 0.f;
        #pragma unroll
        for (int j = 0; j < 16; ++j) {
            float4 cv = cp[j];
            a0 = fmaf(cv.x, wcol[4 * j + 0], a0);
            a1 = fmaf(cv.y, wcol[4 * j + 1], a1);
            a2 = fmaf(cv.z, wcol[4 * j + 2], a2);
            a3 = fmaf(cv.w, wcol[4 * j + 3], a3);
        }
        out[(size_t)m * F_DIM + f] = (a0 + a1) + (a2 + a3);
    }
}

// ---------------- Kernel F: finalize loss (deterministic) ----------------
__global__ void k_loss_final(const float* __restrict__ lossp, float* __restrict__ loss_out) {
    __shared__ float sh[256];
    float s = 0.f;
    for (int i = threadIdx.x; i < M_TOT; i += 256) s += lossp[i];
    sh[threadIdx.x] = s;
    __syncthreads();
    for (int o = 128; o; o >>= 1) {
        if (threadIdx.x < o) sh[threadIdx.x] += sh[threadIdx.x + o];
        __syncthreads();
    }
    if (threadIdx.x == 0)
        loss_out[0] = 1.25f * sh[0] / (float)(M_TOT * C_DIM);
}

extern "C" void kernel_launch(void* const* d_in, const int* in_sizes, int n_in,
                              void* d_out, int out_size, void* d_ws, size_t ws_size,
                              hipStream_t stream) {
    const float* z     = (const float*)d_in[0];
    const float* w_in  = (const float*)d_in[1];
    const float* w_out = (const float*)d_in[2];
    const float* cb    = (const float*)d_in[3];

    float* out    = (float*)d_out;
    float* lossO  = out + (size_t)M_TOT * F_DIM;
    float* idxO   = lossO + 1;
    // gmax (16.8 MB) lives in the d_out 'out' region: written by k_simmax, read
    // by k_pick, then fully overwritten by k_out afterwards (stream-ordered).
    float* gmax   = out;

    float* ws    = (float*)d_ws;                          // total ~9.4 MB
    float* cn    = ws;                                    // 524288 f   (2 MB)
    float* zn    = cn + (size_t)P_DIM * C_DIM;            // 1048576 f  (4 MB)
    float* wT    = zn + (size_t)M_TOT * C_DIM;            // 49152 f
    float* lossp = wT + (size_t)C_DIM * F_DIM;            // 16384 f
    int*   idxi  = (int*)(lossp + M_TOT);                 // 16384 i
    ushort_t* zh = (ushort_t*)(idxi + M_TOT);             // 1048576 us (2 MB)
    ushort_t* ch = zh + (size_t)M_TOT * C_DIM;            // 524288 us  (1 MB)

    k_prep<<<P_DIM / 4 + (C_DIM * F_DIM) / 256, 256, 0, stream>>>(cb, cn, ch, w_out, wT);
    k_proj<<<M_TOT / PBM, 256, 0, stream>>>(z, w_in, zn, zh);

    dim3 gC(M_TOT / 256, NCH);
    k_simmax<<<gC, 256, 0, stream>>>(zh, ch, gmax);
    k_pick<<<M_TOT / 4, 256, 0, stream>>>(gmax, zn, cn, idxi, idxO, lossp);

    dim3 gD(M_TOT / D_ROWS, F_DIM / 64);
    k_out<<<gD, 256, 0, stream>>>(idxi, cn, wT, out);

    k_loss_final<<<1, 256, 0, stream>>>(lossp, lossO);
}

// Round 18
// 185.443 us; speedup vs baseline: 1.0404x; 1.0043x over previous
//
#include <hip/hip_runtime.h>
#include <hip/hip_bf16.h>
#include <math.h>

#define M_TOT   16384      // B*N = 4*4096
#define F_DIM   768
#define C_DIM   64
#define P_DIM   8192
#define EPSN    1e-12f
#define NEG_BIG (-3.402823466e38f)
#define NCH     16
#define PCH     (P_DIM / NCH)   // 512
#define GRP     32
#define NGRP    (P_DIM / GRP)   // 256
#define MARG    1e-2f           // >= 2 * 4e-3 hard bf16x1 screen error bound

typedef __attribute__((ext_vector_type(8))) short bf16x8;
typedef __attribute__((ext_vector_type(4))) float f32x4;
typedef __attribute__((ext_vector_type(16))) float f32x16;
typedef unsigned short ushort_t;
typedef const __attribute__((address_space(1))) void* gas1_t;
typedef __attribute__((address_space(3))) void* las3_t;

__device__ inline ushort_t bf16hi(float v) {
    __hip_bfloat16 hb = __float2bfloat16(v);
    return *reinterpret_cast<ushort_t*>(&hb);
}

// ---------------- Kernel A (merged): codebook norm + w_out transpose ----------
__global__ void k_prep(const float* __restrict__ cb, float* __restrict__ cn,
                       ushort_t* __restrict__ ch, const float* __restrict__ w_out,
                       float* __restrict__ wT) {
    int bx = blockIdx.x;
    if (bx < P_DIM / 4) {
        int wv = threadIdx.x >> 6, lane = threadIdx.x & 63;
        int row = bx * 4 + wv;
        float v = cb[(size_t)row * C_DIM + lane];
        float s = v * v;
        #pragma unroll
        for (int o = 32; o; o >>= 1) s += __shfl_xor(s, o, 64);
        float inv = 1.0f / fmaxf(sqrtf(s), EPSN);
        float nv = v * inv;
        size_t i = (size_t)row * C_DIM + lane;
        cn[i] = nv;
        ch[i] = bf16hi(nv);
    } else {
        int i = (bx - P_DIM / 4) * 256 + threadIdx.x;   // 49152 total
        int f = i >> 6, c = i & 63;
        wT[(size_t)c * F_DIM + f] = w_out[i];
    }
}

// ---------------- Kernel B: zn = l2norm(z @ w_in^T), tiled fp32 GEMM ----------
// r15's proven version. 256 threads (4 waves), 32m x 64c tile. z DIRECT from
// global (4-row broadcast, L1-resident); w via global_load_lds dbuf with
// pre-swizzled source. FMA chain per output is k-ascending x,y,z,w --
// BITWISE identical zn to all passing rounds (idx exactness depends on this).
#define PBM 32
#define PKC 64
__global__ __launch_bounds__(256)
void k_proj(const float* __restrict__ z, const float* __restrict__ w_in,
            float* __restrict__ zn, ushort_t* __restrict__ zh) {
    __shared__ float lw[2][C_DIM * PKC];   // 2 x 16 KB  [c][slot*4]

    const int t  = threadIdx.x;
    const int m0 = blockIdx.x * PBM;
    const int r0 = (t >> 4) * 2;        // rows r0..r0+1  (t>>4 in 0..15)
    const int c0 = (t & 15) * 4;        // cols c0..c0+3
    const int wswz = t & 15;            // == ((c0+cj)>>2)&15 for cj<4

    const float* zrow[2];
    #pragma unroll
    for (int ri = 0; ri < 2; ++ri)
        zrow[ri] = z + (size_t)(m0 + r0 + ri) * F_DIM;

    float acc[2][4];
    #pragma unroll
    for (int i = 0; i < 2; ++i)
        #pragma unroll
        for (int j = 0; j < 4; ++j) acc[i][j] = 0.0f;

    // stage w chunk 0 into buffer 0 (1024 float4 over 256 thr = 4 each)
    #pragma unroll
    for (int i = 0; i < 4; ++i) {
        int f4 = i * 256 + t; int c = f4 >> 4, s4 = f4 & 15;
        __builtin_amdgcn_global_load_lds(
            (gas1_t)(w_in + (size_t)c * F_DIM + (s4 ^ ((c >> 2) & 15)) * 4),
            (las3_t)(&lw[0][f4 * 4]), 16, 0, 0);
    }
    __syncthreads();

    int cur = 0;
    for (int k0 = 0; k0 < F_DIM; k0 += PKC) {       // 12 chunks
        if (k0 + PKC < F_DIM) {                     // issue next-chunk DMA first
            int nxt = cur ^ 1;
            #pragma unroll
            for (int i = 0; i < 4; ++i) {
                int f4 = i * 256 + t; int c = f4 >> 4, s4 = f4 & 15;
                __builtin_amdgcn_global_load_lds(
                    (gas1_t)(w_in + (size_t)c * F_DIM + k0 + PKC
                             + (s4 ^ ((c >> 2) & 15)) * 4),
                    (las3_t)(&lw[nxt][f4 * 4]), 16, 0, 0);
            }
        }

        const float* lwb = lw[cur];
        #pragma unroll
        for (int kq = 0; kq < 16; ++kq) {
            float4 zf[2], wf[4];
            int wo = (kq ^ wswz) * 4;
            #pragma unroll
            for (int ri = 0; ri < 2; ++ri)
                zf[ri] = *(const float4*)(zrow[ri] + k0 + kq * 4);
            #pragma unroll
            for (int cj = 0; cj < 4; ++cj)
                wf[cj] = *(const float4*)(lwb + (c0 + cj) * PKC + wo);
            #pragma unroll
            for (int ri = 0; ri < 2; ++ri)
                #pragma unroll
                for (int cj = 0; cj < 4; ++cj) {
                    acc[ri][cj] = fmaf(zf[ri].x, wf[cj].x, acc[ri][cj]);
                    acc[ri][cj] = fmaf(zf[ri].y, wf[cj].y, acc[ri][cj]);
                    acc[ri][cj] = fmaf(zf[ri].z, wf[cj].z, acc[ri][cj]);
                    acc[ri][cj] = fmaf(zf[ri].w, wf[cj].w, acc[ri][cj]);
                }
        }
        __syncthreads();    // vmcnt(0)+barrier: next w chunk landed, cur free
        cur ^= 1;
    }

    // ---- epilogue: row-norm (16-lane group holds one row's 64 c) ----
    #pragma unroll
    for (int ri = 0; ri < 2; ++ri) {
        float s = acc[ri][0] * acc[ri][0] + acc[ri][1] * acc[ri][1]
                + acc[ri][2] * acc[ri][2] + acc[ri][3] * acc[ri][3];
        #pragma unroll
        for (int o = 1; o < 16; o <<= 1) s += __shfl_xor(s, o, 64);
        float inv = 1.0f / fmaxf(sqrtf(s), EPSN);
        float4 v;
        v.x = acc[ri][0] * inv; v.y = acc[ri][1] * inv;
        v.z = acc[ri][2] * inv; v.w = acc[ri][3] * inv;
        size_t base = (size_t)(m0 + r0 + ri) * C_DIM + c0;
        *(float4*)(zn + base) = v;
        ushort4 hv = {bf16hi(v.x), bf16hi(v.y), bf16hi(v.z), bf16hi(v.w)};
        *(ushort4*)(zh + base) = hv;
    }
}

// ---------------- Kernel C: bf16x1 32x32x16-MFMA screen -> group maxima ----------
// One 32x32x16 MFMA tile = one 32-p group x 32 m. Per group: 4 K-step MFMAs
// (K=64) per m-tile, 2 m-tiles (64 m/wave). D: col=lane&31 (m), rows = the 32
// p's spread over 16 regs x lane-half [m74/m101-verified]; group max = 15-fmax
// tree + shfl_xor(32) -- permutation-invariant over the tile, so only A<->B
// k-consistency matters (same canonical kb=(l>>5)*8 contiguous-k layout as the
// verified 16x16 path). vs 16x16: MFMA cyc/group 80->64, VALU ~50->~34.
__global__ __launch_bounds__(256, 4)
void k_simmax(const ushort_t* __restrict__ zh, const ushort_t* __restrict__ ch,
              float* __restrict__ gmax) {
    int wv = threadIdx.x >> 6, l = threadIdx.x & 63;
    int m0 = (blockIdx.x * 4 + wv) * 64;
    int p0 = blockIdx.y * PCH;
    int ln = l & 31;            // A row (p) / B col (m)
    int kb = (l >> 5) * 8;      // k-half selector

    // B frags: zh rows m0 + mt*32 + ln; K-step st covers k = st*16 + kb + 0..7
    bf16x8 bh[2][4];
    #pragma unroll
    for (int mt = 0; mt < 2; ++mt) {
        const ushort_t* zr = zh + (size_t)(m0 + mt * 32 + ln) * C_DIM + kb;
        #pragma unroll
        for (int st = 0; st < 4; ++st)
            bh[mt][st] = *(const bf16x8*)(zr + st * 16);
    }

    for (int g = 0; g < PCH / GRP; ++g) {           // 16 groups of 32 p
        const ushort_t* ar = ch + (size_t)(p0 + g * 32 + ln) * C_DIM + kb;
        bf16x8 a0 = *(const bf16x8*)(ar);
        bf16x8 a1 = *(const bf16x8*)(ar + 16);
        bf16x8 a2 = *(const bf16x8*)(ar + 32);
        bf16x8 a3 = *(const bf16x8*)(ar + 48);

        #pragma unroll
        for (int mt = 0; mt < 2; ++mt) {
            f32x16 acc = {0.f, 0.f, 0.f, 0.f, 0.f, 0.f, 0.f, 0.f,
                          0.f, 0.f, 0.f, 0.f, 0.f, 0.f, 0.f, 0.f};
            acc = __builtin_amdgcn_mfma_f32_32x32x16_bf16(a0, bh[mt][0], acc, 0, 0, 0);
            acc = __builtin_amdgcn_mfma_f32_32x32x16_bf16(a1, bh[mt][1], acc, 0, 0, 0);
            acc = __builtin_amdgcn_mfma_f32_32x32x16_bf16(a2, bh[mt][2], acc, 0, 0, 0);
            acc = __builtin_amdgcn_mfma_f32_32x32x16_bf16(a3, bh[mt][3], acc, 0, 0, 0);
            // max over this lane's 16 p-rows, then combine lane-halves
            float v0 = fmaxf(acc[0], acc[1]),   v1 = fmaxf(acc[2], acc[3]);
            float v2 = fmaxf(acc[4], acc[5]),   v3 = fmaxf(acc[6], acc[7]);
            float v4 = fmaxf(acc[8], acc[9]),   v5 = fmaxf(acc[10], acc[11]);
            float v6 = fmaxf(acc[12], acc[13]), v7 = fmaxf(acc[14], acc[15]);
            float v = fmaxf(fmaxf(fmaxf(v0, v1), fmaxf(v2, v3)),
                            fmaxf(fmaxf(v4, v5), fmaxf(v6, v7)));
            v = fmaxf(v, __shfl_xor(v, 32, 64));
            if (l < 32)
                gmax[(size_t)(blockIdx.y * (PCH / GRP) + g) * M_TOT
                     + m0 + mt * 32 + ln] = v;
        }
    }
}

// ---------------- Kernel C2: per-row pick + fused loss partial ----------
// One wave per row. Lane l holds groups {l, l+64, l+128, l+192}. Row max via
// shuffle; __ballot flags candidates; wave-parallel exact fp32 rescan (np tie
// rules: groups ascending, strict >, min p). Fused (zn-cn[bp])^2 partial.
__global__ __launch_bounds__(256)
void k_pick(const float* __restrict__ gmax, const float* __restrict__ zn,
            const float* __restrict__ cn, int* __restrict__ idx_i,
            float* __restrict__ idx_f, float* __restrict__ lossp) {
    int wv = threadIdx.x >> 6, l = threadIdx.x & 63;
    int m = blockIdx.x * 4 + wv;            // one wave per row

    float gv[4];
    #pragma unroll
    for (int b = 0; b < 4; ++b)
        gv[b] = gmax[(size_t)(b * 64 + l) * M_TOT + m];
    float rm = fmaxf(fmaxf(gv[0], gv[1]), fmaxf(gv[2], gv[3]));
    #pragma unroll
    for (int o = 32; o; o >>= 1) rm = fmaxf(rm, __shfl_xor(rm, o, 64));
    float thr = rm - MARG;

    // zn row: lane holds half the row (half = l>>5)
    float zr[32];
    {
        const float4* zp = (const float4*)(zn + (size_t)m * C_DIM + (l >> 5) * 32);
        #pragma unroll
        for (int q = 0; q < 8; ++q) {
            float4 v = zp[q];
            zr[4 * q] = v.x; zr[4 * q + 1] = v.y;
            zr[4 * q + 2] = v.z; zr[4 * q + 3] = v.w;
        }
    }

    float bv = NEG_BIG; int bp = P_DIM;
    #pragma unroll
    for (int b = 0; b < 4; ++b) {           // ascending batches -> ascending groups
        unsigned long long mask = __ballot(gv[b] >= thr);
        while (mask) {
            int j = __ffsll((unsigned long long)mask) - 1;
            mask &= mask - 1;               // ascending j within batch
            int g = b * 64 + j;
            int p = g * GRP + (l & 31);
            const float4* cp = (const float4*)(cn + (size_t)p * C_DIM + (l >> 5) * 32);
            float a0 = 0.f, a1 = 0.f, a2 = 0.f, a3 = 0.f;
            #pragma unroll
            for (int q = 0; q < 8; ++q) {
                float4 w = cp[q];
                a0 = fmaf(w.x, zr[4 * q + 0], a0);
                a1 = fmaf(w.y, zr[4 * q + 1], a1);
                a2 = fmaf(w.z, zr[4 * q + 2], a2);
                a3 = fmaf(w.w, zr[4 * q + 3], a3);
            }
            float s = (a0 + a1) + (a2 + a3);
            s += __shfl_xor(s, 32, 64);     // combine halves: full dot in both lanes
            if (s > bv || (s == bv && p < bp)) { bv = s; bp = p; }
        }
    }
    #pragma unroll
    for (int o = 32; o; o >>= 1) {
        float ov = __shfl_xor(bv, o, 64);
        int   op = __shfl_xor(bp, o, 64);
        if (ov > bv || (ov == bv && op < bp)) { bv = ov; bp = op; }
    }
    if (l == 0) { idx_i[m] = bp; idx_f[m] = (float)bp; }

    // fused loss partial: sum (zn - cn[bp])^2 over the row (bp wave-uniform)
    {
        const float4* cp = (const float4*)(cn + (size_t)bp * C_DIM + (l >> 5) * 32);
        float d2 = 0.f;
        #pragma unroll
        for (int q = 0; q < 8; ++q) {
            float4 w = cp[q];
            float dx = zr[4 * q + 0] - w.x; d2 = fmaf(dx, dx, d2);
            float dy = zr[4 * q + 1] - w.y; d2 = fmaf(dy, dy, d2);
            float dz = zr[4 * q + 2] - w.z; d2 = fmaf(dz, dz, d2);
            float dw = zr[4 * q + 3] - w.w; d2 = fmaf(dw, dw, d2);
        }
        d2 += __shfl_xor(d2, 32, 64);
        if (l == 0) lossp[m] = d2;
    }
}

// ---------------- Kernel D: out = codes @ w_outT, 4 independent FMA chains ----
#define D_ROWS 128
__global__ void k_out(const int* __restrict__ idx, const float* __restrict__ cn,
                      const float* __restrict__ wT, float* __restrict__ out) {
    int wv = threadIdx.x >> 6, lane = threadIdx.x & 63;
    int f  = blockIdx.y * 64 + lane;
    int m0 = blockIdx.x * D_ROWS + wv * 32;

    float wcol[64];
    #pragma unroll
    for (int c = 0; c < 64; ++c) wcol[c] = wT[(size_t)c * F_DIM + f];

    #pragma unroll 4
    for (int r = 0; r < 32; ++r) {
        int m = __builtin_amdgcn_readfirstlane(m0 + r);
        const float4* cp = (const float4*)(cn + (size_t)idx[m] * C_DIM);
        float a0 = 0.f, a1 = 0.f, a2 = 0.f, a3 = 0.f;
        #pragma unroll
        for (int j = 0; j < 16; ++j) {
            float4 cv = cp[j];
            a0 = fmaf(cv.x, wcol[4 * j + 0], a0);
            a1 = fmaf(cv.y, wcol[4 * j + 1], a1);
            a2 = fmaf(cv.z, wcol[4 * j + 2], a2);
            a3 = fmaf(cv.w, wcol[4 * j + 3], a3);
        }
        out[(size_t)m * F_DIM + f] = (a0 + a1) + (a2 + a3);
    }
}

// ---------------- Kernel F: finalize loss (deterministic) ----------------
__global__ void k_loss_final(const float* __restrict__ lossp, float* __restrict__ loss_out) {
    __shared__ float sh[256];
    float s = 0.f;
    for (int i = threadIdx.x; i < M_TOT; i += 256) s += lossp[i];
    sh[threadIdx.x] = s;
    __syncthreads();
    for (int o = 128; o; o >>= 1) {
        if (threadIdx.x < o) sh[threadIdx.x] += sh[threadIdx.x + o];
        __syncthreads();
    }
    if (threadIdx.x == 0)
        loss_out[0] = 1.25f * sh[0] / (float)(M_TOT * C_DIM);
}

extern "C" void kernel_launch(void* const* d_in, const int* in_sizes, int n_in,
                              void* d_out, int out_size, void* d_ws, size_t ws_size,
                              hipStream_t stream) {
    const float* z     = (const float*)d_in[0];
    const float* w_in  = (const float*)d_in[1];
    const float* w_out = (const float*)d_in[2];
    const float* cb    = (const float*)d_in[3];

    float* out    = (float*)d_out;
    float* lossO  = out + (size_t)M_TOT * F_DIM;
    float* idxO   = lossO + 1;
    // gmax (16.8 MB) lives in the d_out 'out' region: written by k_simmax, read
    // by k_pick, then fully overwritten by k_out afterwards (stream-ordered).
    float* gmax   = out;

    float* ws    = (float*)d_ws;                          // total ~9.4 MB
    float* cn    = ws;                                    // 524288 f   (2 MB)
    float* zn    = cn + (size_t)P_DIM * C_DIM;            // 1048576 f  (4 MB)
    float* wT    = zn + (size_t)M_TOT * C_DIM;            // 49152 f
    float* lossp = wT + (size_t)C_DIM * F_DIM;            // 16384 f
    int*   idxi  = (int*)(lossp + M_TOT);                 // 16384 i
    ushort_t* zh = (ushort_t*)(idxi + M_TOT);             // 1048576 us (2 MB)
    ushort_t* ch = zh + (size_t)M_TOT * C_DIM;            // 524288 us  (1 MB)

    k_prep<<<P_DIM / 4 + (C_DIM * F_DIM) / 256, 256, 0, stream>>>(cb, cn, ch, w_out, wT);
    k_proj<<<M_TOT / PBM, 256, 0, stream>>>(z, w_in, zn, zh);

    dim3 gC(M_TOT / 256, NCH);
    k_simmax<<<gC, 256, 0, stream>>>(zh, ch, gmax);
    k_pick<<<M_TOT / 4, 256, 0, stream>>>(gmax, zn, cn, idxi, idxO, lossp);

    dim3 gD(M_TOT / D_ROWS, F_DIM / 64);
    k_out<<<gD, 256, 0, stream>>>(idxi, cn, wT, out);

    k_loss_final<<<1, 256, 0, stream>>>(lossp, lossO);
}

// Round 19
// 170.219 us; speedup vs baseline: 1.1335x; 1.0894x over previous
//
#include <hip/hip_runtime.h>
#include <hip/hip_bf16.h>
#include <math.h>

#define M_TOT   16384      // B*N = 4*4096
#define F_DIM   768
#define C_DIM   64
#define P_DIM   8192
#define EPSN    1e-12f
#define NEG_BIG (-3.402823466e38f)
#define NCH     16
#define PCH     (P_DIM / NCH)   // 512
#define GRP     32
#define NGRP    (P_DIM / GRP)   // 256
#define MARG    1e-2f           // >= 2 * 4e-3 hard bf16x1 screen error bound

typedef __attribute__((ext_vector_type(8))) short bf16x8;
typedef __attribute__((ext_vector_type(4))) float f32x4;
typedef __attribute__((ext_vector_type(16))) float f32x16;
typedef unsigned short ushort_t;
typedef const __attribute__((address_space(1))) void* gas1_t;
typedef __attribute__((address_space(3))) void* las3_t;

__device__ inline ushort_t bf16hi(float v) {
    __hip_bfloat16 hb = __float2bfloat16(v);
    return *reinterpret_cast<ushort_t*>(&hb);
}

// ---------------- Kernel B (merged with prep): proj + cb-norm + wout-T ----------
// blocks [0,512): r15's proven proj tile (bitwise-identical zn).
// blocks [512, 512+2048): cn = l2norm(codebook) + bf16 round.
// blocks [512+2048, +192): wT[c][f] = w_out[f][c].
// Prep blocks fill scheduler holes around proj's 2-blocks/CU residency.
#define PBM 32
#define PKC 64
#define PROJ_BLKS (M_TOT / PBM)             // 512
__global__ __launch_bounds__(256)
void k_proj(const float* __restrict__ z, const float* __restrict__ w_in,
            float* __restrict__ zn, ushort_t* __restrict__ zh,
            const float* __restrict__ cb, float* __restrict__ cn,
            ushort_t* __restrict__ ch, const float* __restrict__ w_out,
            float* __restrict__ wT) {
    __shared__ float lw[2][C_DIM * PKC];   // 2 x 16 KB  [c][slot*4]

    const int bx = blockIdx.x;
    if (bx >= PROJ_BLKS) {
        int pb = bx - PROJ_BLKS;
        if (pb < P_DIM / 4) {
            int wv = threadIdx.x >> 6, lane = threadIdx.x & 63;
            int row = pb * 4 + wv;
            float v = cb[(size_t)row * C_DIM + lane];
            float s = v * v;
            #pragma unroll
            for (int o = 32; o; o >>= 1) s += __shfl_xor(s, o, 64);
            float inv = 1.0f / fmaxf(sqrtf(s), EPSN);
            float nv = v * inv;
            size_t i = (size_t)row * C_DIM + lane;
            cn[i] = nv;
            ch[i] = bf16hi(nv);
        } else {
            int i = (pb - P_DIM / 4) * 256 + threadIdx.x;   // 49152 total
            int f = i >> 6, c = i & 63;
            wT[(size_t)c * F_DIM + f] = w_out[i];
        }
        return;
    }

    const int t  = threadIdx.x;
    const int m0 = bx * PBM;
    const int r0 = (t >> 4) * 2;        // rows r0..r0+1  (t>>4 in 0..15)
    const int c0 = (t & 15) * 4;        // cols c0..c0+3
    const int wswz = t & 15;            // == ((c0+cj)>>2)&15 for cj<4

    const float* zrow[2];
    #pragma unroll
    for (int ri = 0; ri < 2; ++ri)
        zrow[ri] = z + (size_t)(m0 + r0 + ri) * F_DIM;

    float acc[2][4];
    #pragma unroll
    for (int i = 0; i < 2; ++i)
        #pragma unroll
        for (int j = 0; j < 4; ++j) acc[i][j] = 0.0f;

    // stage w chunk 0 into buffer 0 (1024 float4 over 256 thr = 4 each)
    #pragma unroll
    for (int i = 0; i < 4; ++i) {
        int f4 = i * 256 + t; int c = f4 >> 4, s4 = f4 & 15;
        __builtin_amdgcn_global_load_lds(
            (gas1_t)(w_in + (size_t)c * F_DIM + (s4 ^ ((c >> 2) & 15)) * 4),
            (las3_t)(&lw[0][f4 * 4]), 16, 0, 0);
    }
    __syncthreads();

    int cur = 0;
    for (int k0 = 0; k0 < F_DIM; k0 += PKC) {       // 12 chunks
        if (k0 + PKC < F_DIM) {                     // issue next-chunk DMA first
            int nxt = cur ^ 1;
            #pragma unroll
            for (int i = 0; i < 4; ++i) {
                int f4 = i * 256 + t; int c = f4 >> 4, s4 = f4 & 15;
                __builtin_amdgcn_global_load_lds(
                    (gas1_t)(w_in + (size_t)c * F_DIM + k0 + PKC
                             + (s4 ^ ((c >> 2) & 15)) * 4),
                    (las3_t)(&lw[nxt][f4 * 4]), 16, 0, 0);
            }
        }

        const float* lwb = lw[cur];
        #pragma unroll
        for (int kq = 0; kq < 16; ++kq) {
            float4 zf[2], wf[4];
            int wo = (kq ^ wswz) * 4;
            #pragma unroll
            for (int ri = 0; ri < 2; ++ri)
                zf[ri] = *(const float4*)(zrow[ri] + k0 + kq * 4);
            #pragma unroll
            for (int cj = 0; cj < 4; ++cj)
                wf[cj] = *(const float4*)(lwb + (c0 + cj) * PKC + wo);
            #pragma unroll
            for (int ri = 0; ri < 2; ++ri)
                #pragma unroll
                for (int cj = 0; cj < 4; ++cj) {
                    acc[ri][cj] = fmaf(zf[ri].x, wf[cj].x, acc[ri][cj]);
                    acc[ri][cj] = fmaf(zf[ri].y, wf[cj].y, acc[ri][cj]);
                    acc[ri][cj] = fmaf(zf[ri].z, wf[cj].z, acc[ri][cj]);
                    acc[ri][cj] = fmaf(zf[ri].w, wf[cj].w, acc[ri][cj]);
                }
        }
        __syncthreads();    // vmcnt(0)+barrier: next w chunk landed, cur free
        cur ^= 1;
    }

    // ---- epilogue: row-norm (16-lane group holds one row's 64 c) ----
    #pragma unroll
    for (int ri = 0; ri < 2; ++ri) {
        float s = acc[ri][0] * acc[ri][0] + acc[ri][1] * acc[ri][1]
                + acc[ri][2] * acc[ri][2] + acc[ri][3] * acc[ri][3];
        #pragma unroll
        for (int o = 1; o < 16; o <<= 1) s += __shfl_xor(s, o, 64);
        float inv = 1.0f / fmaxf(sqrtf(s), EPSN);
        float4 v;
        v.x = acc[ri][0] * inv; v.y = acc[ri][1] * inv;
        v.z = acc[ri][2] * inv; v.w = acc[ri][3] * inv;
        size_t base = (size_t)(m0 + r0 + ri) * C_DIM + c0;
        *(float4*)(zn + base) = v;
        ushort4 hv = {bf16hi(v.x), bf16hi(v.y), bf16hi(v.z), bf16hi(v.w)};
        *(ushort4*)(zh + base) = hv;
    }
}

// ---------------- Kernel C: bf16x1 32x32x16-MFMA screen -> group maxima ----------
// r18's proven version. D: col=lane&31 (m) [m74/m101-verified]; group max is
// permutation-invariant over the tile -> only A<->B k-consistency matters.
__global__ __launch_bounds__(256, 4)
void k_simmax(const ushort_t* __restrict__ zh, const ushort_t* __restrict__ ch,
              float* __restrict__ gmax) {
    int wv = threadIdx.x >> 6, l = threadIdx.x & 63;
    int m0 = (blockIdx.x * 4 + wv) * 64;
    int p0 = blockIdx.y * PCH;
    int ln = l & 31;            // A row (p) / B col (m)
    int kb = (l >> 5) * 8;      // k-half selector

    bf16x8 bh[2][4];
    #pragma unroll
    for (int mt = 0; mt < 2; ++mt) {
        const ushort_t* zr = zh + (size_t)(m0 + mt * 32 + ln) * C_DIM + kb;
        #pragma unroll
        for (int st = 0; st < 4; ++st)
            bh[mt][st] = *(const bf16x8*)(zr + st * 16);
    }

    for (int g = 0; g < PCH / GRP; ++g) {           // 16 groups of 32 p
        const ushort_t* ar = ch + (size_t)(p0 + g * 32 + ln) * C_DIM + kb;
        bf16x8 a0 = *(const bf16x8*)(ar);
        bf16x8 a1 = *(const bf16x8*)(ar + 16);
        bf16x8 a2 = *(const bf16x8*)(ar + 32);
        bf16x8 a3 = *(const bf16x8*)(ar + 48);

        #pragma unroll
        for (int mt = 0; mt < 2; ++mt) {
            f32x16 acc = {0.f, 0.f, 0.f, 0.f, 0.f, 0.f, 0.f, 0.f,
                          0.f, 0.f, 0.f, 0.f, 0.f, 0.f, 0.f, 0.f};
            acc = __builtin_amdgcn_mfma_f32_32x32x16_bf16(a0, bh[mt][0], acc, 0, 0, 0);
            acc = __builtin_amdgcn_mfma_f32_32x32x16_bf16(a1, bh[mt][1], acc, 0, 0, 0);
            acc = __builtin_amdgcn_mfma_f32_32x32x16_bf16(a2, bh[mt][2], acc, 0, 0, 0);
            acc = __builtin_amdgcn_mfma_f32_32x32x16_bf16(a3, bh[mt][3], acc, 0, 0, 0);
            float v0 = fmaxf(acc[0], acc[1]),   v1 = fmaxf(acc[2], acc[3]);
            float v2 = fmaxf(acc[4], acc[5]),   v3 = fmaxf(acc[6], acc[7]);
            float v4 = fmaxf(acc[8], acc[9]),   v5 = fmaxf(acc[10], acc[11]);
            float v6 = fmaxf(acc[12], acc[13]), v7 = fmaxf(acc[14], acc[15]);
            float v = fmaxf(fmaxf(fmaxf(v0, v1), fmaxf(v2, v3)),
                            fmaxf(fmaxf(v4, v5), fmaxf(v6, v7)));
            v = fmaxf(v, __shfl_xor(v, 32, 64));
            if (l < 32)
                gmax[(size_t)(blockIdx.y * (PCH / GRP) + g) * M_TOT
                     + m0 + mt * 32 + ln] = v;
        }
    }
}

// ---------------- Kernel C2: per-row pick + fused loss partial ----------
__global__ __launch_bounds__(256)
void k_pick(const float* __restrict__ gmax, const float* __restrict__ zn,
            const float* __restrict__ cn, int* __restrict__ idx_i,
            float* __restrict__ idx_f, float* __restrict__ lossp) {
    int wv = threadIdx.x >> 6, l = threadIdx.x & 63;
    int m = blockIdx.x * 4 + wv;            // one wave per row

    float gv[4];
    #pragma unroll
    for (int b = 0; b < 4; ++b)
        gv[b] = gmax[(size_t)(b * 64 + l) * M_TOT + m];
    float rm = fmaxf(fmaxf(gv[0], gv[1]), fmaxf(gv[2], gv[3]));
    #pragma unroll
    for (int o = 32; o; o >>= 1) rm = fmaxf(rm, __shfl_xor(rm, o, 64));
    float thr = rm - MARG;

    float zr[32];
    {
        const float4* zp = (const float4*)(zn + (size_t)m * C_DIM + (l >> 5) * 32);
        #pragma unroll
        for (int q = 0; q < 8; ++q) {
            float4 v = zp[q];
            zr[4 * q] = v.x; zr[4 * q + 1] = v.y;
            zr[4 * q + 2] = v.z; zr[4 * q + 3] = v.w;
        }
    }

    float bv = NEG_BIG; int bp = P_DIM;
    #pragma unroll
    for (int b = 0; b < 4; ++b) {           // ascending batches -> ascending groups
        unsigned long long mask = __ballot(gv[b] >= thr);
        while (mask) {
            int j = __ffsll((unsigned long long)mask) - 1;
            mask &= mask - 1;               // ascending j within batch
            int g = b * 64 + j;
            int p = g * GRP + (l & 31);
            const float4* cp = (const float4*)(cn + (size_t)p * C_DIM + (l >> 5) * 32);
            float a0 = 0.f, a1 = 0.f, a2 = 0.f, a3 = 0.f;
            #pragma unroll
            for (int q = 0; q < 8; ++q) {
                float4 w = cp[q];
                a0 = fmaf(w.x, zr[4 * q + 0], a0);
                a1 = fmaf(w.y, zr[4 * q + 1], a1);
                a2 = fmaf(w.z, zr[4 * q + 2], a2);
                a3 = fmaf(w.w, zr[4 * q + 3], a3);
            }
            float s = (a0 + a1) + (a2 + a3);
            s += __shfl_xor(s, 32, 64);     // combine halves: full dot in both lanes
            if (s > bv || (s == bv && p < bp)) { bv = s; bp = p; }
        }
    }
    #pragma unroll
    for (int o = 32; o; o >>= 1) {
        float ov = __shfl_xor(bv, o, 64);
        int   op = __shfl_xor(bp, o, 64);
        if (ov > bv || (ov == bv && op < bp)) { bv = ov; bp = op; }
    }
    if (l == 0) { idx_i[m] = bp; idx_f[m] = (float)bp; }

    // fused loss partial: sum (zn - cn[bp])^2 over the row (bp wave-uniform)
    {
        const float4* cp = (const float4*)(cn + (size_t)bp * C_DIM + (l >> 5) * 32);
        float d2 = 0.f;
        #pragma unroll
        for (int q = 0; q < 8; ++q) {
            float4 w = cp[q];
            float dx = zr[4 * q + 0] - w.x; d2 = fmaf(dx, dx, d2);
            float dy = zr[4 * q + 1] - w.y; d2 = fmaf(dy, dy, d2);
            float dz = zr[4 * q + 2] - w.z; d2 = fmaf(dz, dz, d2);
            float dw = zr[4 * q + 3] - w.w; d2 = fmaf(dw, dw, d2);
        }
        d2 += __shfl_xor(d2, 32, 64);
        if (l == 0) lossp[m] = d2;
    }
}

// ---------------- Kernel D (merged with loss-final): out + loss reduce ----------
// Flattened 1D grid: blocks [0,1536) = decode tiles (m = bx%128, f = bx/128);
// block 1536 = deterministic loss reduction (lossp complete before launch).
#define D_ROWS 128
#define D_BLKS (M_TOT / D_ROWS * (F_DIM / 64))      // 1536
__global__ void k_out(const int* __restrict__ idx, const float* __restrict__ cn,
                      const float* __restrict__ wT, float* __restrict__ out,
                      const float* __restrict__ lossp, float* __restrict__ loss_out) {
    __shared__ float sh[256];
    int bx = blockIdx.x;
    if (bx >= D_BLKS) {
        float s = 0.f;
        for (int i = threadIdx.x; i < M_TOT; i += 256) s += lossp[i];
        sh[threadIdx.x] = s;
        __syncthreads();
        for (int o = 128; o; o >>= 1) {
            if (threadIdx.x < o) sh[threadIdx.x] += sh[threadIdx.x + o];
            __syncthreads();
        }
        if (threadIdx.x == 0)
            loss_out[0] = 1.25f * sh[0] / (float)(M_TOT * C_DIM);
        return;
    }

    int wv = threadIdx.x >> 6, lane = threadIdx.x & 63;
    int f  = (bx >> 7) * 64 + lane;     // bx/128 in 0..11
    int m0 = (bx & 127) * D_ROWS + wv * 32;

    float wcol[64];
    #pragma unroll
    for (int c = 0; c < 64; ++c) wcol[c] = wT[(size_t)c * F_DIM + f];

    #pragma unroll 4
    for (int r = 0; r < 32; ++r) {
        int m = __builtin_amdgcn_readfirstlane(m0 + r);
        const float4* cp = (const float4*)(cn + (size_t)idx[m] * C_DIM);
        float a0 = 0.f, a1 = 0.f, a2 = 0.f, a3 = 0.f;
        #pragma unroll
        for (int j = 0; j < 16; ++j) {
            float4 cv = cp[j];
            a0 = fmaf(cv.x, wcol[4 * j + 0], a0);
            a1 = fmaf(cv.y, wcol[4 * j + 1], a1);
            a2 = fmaf(cv.z, wcol[4 * j + 2], a2);
            a3 = fmaf(cv.w, wcol[4 * j + 3], a3);
        }
        out[(size_t)m * F_DIM + f] = (a0 + a1) + (a2 + a3);
    }
}

extern "C" void kernel_launch(void* const* d_in, const int* in_sizes, int n_in,
                              void* d_out, int out_size, void* d_ws, size_t ws_size,
                              hipStream_t stream) {
    const float* z     = (const float*)d_in[0];
    const float* w_in  = (const float*)d_in[1];
    const float* w_out = (const float*)d_in[2];
    const float* cb    = (const float*)d_in[3];

    float* out    = (float*)d_out;
    float* lossO  = out + (size_t)M_TOT * F_DIM;
    float* idxO   = lossO + 1;
    // gmax (16.8 MB) lives in the d_out 'out' region: written by k_simmax, read
    // by k_pick, then fully overwritten by k_out afterwards (stream-ordered).
    float* gmax   = out;

    float* ws    = (float*)d_ws;                          // total ~9.4 MB
    float* cn    = ws;                                    // 524288 f   (2 MB)
    float* zn    = cn + (size_t)P_DIM * C_DIM;            // 1048576 f  (4 MB)
    float* wT    = zn + (size_t)M_TOT * C_DIM;            // 49152 f
    float* lossp = wT + (size_t)C_DIM * F_DIM;            // 16384 f
    int*   idxi  = (int*)(lossp + M_TOT);                 // 16384 i
    ushort_t* zh = (ushort_t*)(idxi + M_TOT);             // 1048576 us (2 MB)
    ushort_t* ch = zh + (size_t)M_TOT * C_DIM;            // 524288 us  (1 MB)

    int projGrid = PROJ_BLKS + P_DIM / 4 + (C_DIM * F_DIM) / 256;   // 512+2048+192
    k_proj<<<projGrid, 256, 0, stream>>>(z, w_in, zn, zh, cb, cn, ch, w_out, wT);

    dim3 gC(M_TOT / 256, NCH);
    k_simmax<<<gC, 256, 0, stream>>>(zh, ch, gmax);
    k_pick<<<M_TOT / 4, 256, 0, stream>>>(gmax, zn, cn, idxi, idxO, lossp);

    k_out<<<D_BLKS + 1, 256, 0, stream>>>(idxi, cn, wT, out, lossp, lossO);
}

// Round 20
// 154.779 us; speedup vs baseline: 1.2465x; 1.0998x over previous
//
#include <hip/hip_runtime.h>
#include <hip/hip_bf16.h>
#include <math.h>

#define M_TOT   16384      // B*N = 4*4096
#define F_DIM   768
#define C_DIM   64
#define P_DIM   8192
#define EPSN    1e-12f
#define NEG_BIG (-3.402823466e38f)
#define NCH     16
#define PCH     (P_DIM / NCH)   // 512
#define GRP     32
#define NGRP    (P_DIM / GRP)   // 256
#define MARG    1e-2f           // >= 2 * 4e-3 hard bf16x1 screen error bound

typedef __attribute__((ext_vector_type(8))) short bf16x8;
typedef __attribute__((ext_vector_type(4))) float f32x4;
typedef __attribute__((ext_vector_type(16))) float f32x16;
typedef unsigned short ushort_t;
typedef const __attribute__((address_space(1))) void* gas1_t;
typedef __attribute__((address_space(3))) void* las3_t;

__device__ inline ushort_t bf16hi(float v) {
    __hip_bfloat16 hb = __float2bfloat16(v);
    return *reinterpret_cast<ushort_t*>(&hb);
}

// MFMA-fragment-order layout for the bf16 screen operands:
//   frag[(row>>5)*8 + (k>>4)*2 + ((k>>3)&1)] [ (row&31)*8 + (k&7) ]
// (2048 ushorts per 32-row tile). A wave's fragment load for (tile, st) is
// base + l*8 ushorts -> one contiguous 1KB segment (fully coalesced); lane l
// receives exactly the values it previously gathered -> screen bitwise same.
__device__ inline size_t fragAddr(int row, int k) {
    return ((size_t)(row >> 5) * 8 + (k >> 4) * 2 + ((k >> 3) & 1)) * 256
         + (row & 31) * 8 + (k & 7);
}

// ---------------- Kernel B (merged with prep): proj + cb-norm + wout-T ----------
#define PBM 32
#define PKC 64
#define PROJ_BLKS (M_TOT / PBM)             // 512
__global__ __launch_bounds__(256)
void k_proj(const float* __restrict__ z, const float* __restrict__ w_in,
            float* __restrict__ zn, ushort_t* __restrict__ zhF,
            const float* __restrict__ cb, float* __restrict__ cn,
            ushort_t* __restrict__ chF, const float* __restrict__ w_out,
            float* __restrict__ wT) {
    __shared__ float lw[2][C_DIM * PKC];   // 2 x 16 KB  [c][slot*4]

    const int bx = blockIdx.x;
    if (bx >= PROJ_BLKS) {
        int pb = bx - PROJ_BLKS;
        if (pb < P_DIM / 4) {
            int wv = threadIdx.x >> 6, lane = threadIdx.x & 63;
            int row = pb * 4 + wv;
            float v = cb[(size_t)row * C_DIM + lane];
            float s = v * v;
            #pragma unroll
            for (int o = 32; o; o >>= 1) s += __shfl_xor(s, o, 64);
            float inv = 1.0f / fmaxf(sqrtf(s), EPSN);
            float nv = v * inv;
            cn[(size_t)row * C_DIM + lane] = nv;
            chF[fragAddr(row, lane)] = bf16hi(nv);
        } else {
            int i = (pb - P_DIM / 4) * 256 + threadIdx.x;   // 49152 total
            int f = i >> 6, c = i & 63;
            wT[(size_t)c * F_DIM + f] = w_out[i];
        }
        return;
    }

    const int t  = threadIdx.x;
    const int m0 = bx * PBM;
    const int r0 = (t >> 4) * 2;        // rows r0..r0+1  (t>>4 in 0..15)
    const int c0 = (t & 15) * 4;        // cols c0..c0+3
    const int wswz = t & 15;            // == ((c0+cj)>>2)&15 for cj<4

    const float* zrow[2];
    #pragma unroll
    for (int ri = 0; ri < 2; ++ri)
        zrow[ri] = z + (size_t)(m0 + r0 + ri) * F_DIM;

    float acc[2][4];
    #pragma unroll
    for (int i = 0; i < 2; ++i)
        #pragma unroll
        for (int j = 0; j < 4; ++j) acc[i][j] = 0.0f;

    // stage w chunk 0 into buffer 0 (1024 float4 over 256 thr = 4 each)
    #pragma unroll
    for (int i = 0; i < 4; ++i) {
        int f4 = i * 256 + t; int c = f4 >> 4, s4 = f4 & 15;
        __builtin_amdgcn_global_load_lds(
            (gas1_t)(w_in + (size_t)c * F_DIM + (s4 ^ ((c >> 2) & 15)) * 4),
            (las3_t)(&lw[0][f4 * 4]), 16, 0, 0);
    }
    __syncthreads();

    int cur = 0;
    for (int k0 = 0; k0 < F_DIM; k0 += PKC) {       // 12 chunks
        if (k0 + PKC < F_DIM) {                     // issue next-chunk DMA first
            int nxt = cur ^ 1;
            #pragma unroll
            for (int i = 0; i < 4; ++i) {
                int f4 = i * 256 + t; int c = f4 >> 4, s4 = f4 & 15;
                __builtin_amdgcn_global_load_lds(
                    (gas1_t)(w_in + (size_t)c * F_DIM + k0 + PKC
                             + (s4 ^ ((c >> 2) & 15)) * 4),
                    (las3_t)(&lw[nxt][f4 * 4]), 16, 0, 0);
            }
        }

        const float* lwb = lw[cur];
        #pragma unroll
        for (int kq = 0; kq < 16; ++kq) {
            float4 zf[2], wf[4];
            int wo = (kq ^ wswz) * 4;
            #pragma unroll
            for (int ri = 0; ri < 2; ++ri)
                zf[ri] = *(const float4*)(zrow[ri] + k0 + kq * 4);
            #pragma unroll
            for (int cj = 0; cj < 4; ++cj)
                wf[cj] = *(const float4*)(lwb + (c0 + cj) * PKC + wo);
            #pragma unroll
            for (int ri = 0; ri < 2; ++ri)
                #pragma unroll
                for (int cj = 0; cj < 4; ++cj) {
                    acc[ri][cj] = fmaf(zf[ri].x, wf[cj].x, acc[ri][cj]);
                    acc[ri][cj] = fmaf(zf[ri].y, wf[cj].y, acc[ri][cj]);
                    acc[ri][cj] = fmaf(zf[ri].z, wf[cj].z, acc[ri][cj]);
                    acc[ri][cj] = fmaf(zf[ri].w, wf[cj].w, acc[ri][cj]);
                }
        }
        __syncthreads();    // vmcnt(0)+barrier: next w chunk landed, cur free
        cur ^= 1;
    }

    // ---- epilogue: row-norm; zn unchanged (bitwise), zh scattered to frag order
    #pragma unroll
    for (int ri = 0; ri < 2; ++ri) {
        float s = acc[ri][0] * acc[ri][0] + acc[ri][1] * acc[ri][1]
                + acc[ri][2] * acc[ri][2] + acc[ri][3] * acc[ri][3];
        #pragma unroll
        for (int o = 1; o < 16; o <<= 1) s += __shfl_xor(s, o, 64);
        float inv = 1.0f / fmaxf(sqrtf(s), EPSN);
        float4 v;
        v.x = acc[ri][0] * inv; v.y = acc[ri][1] * inv;
        v.z = acc[ri][2] * inv; v.w = acc[ri][3] * inv;
        int m = m0 + r0 + ri;
        *(float4*)(zn + (size_t)m * C_DIM + c0) = v;
        ushort4 hv = {bf16hi(v.x), bf16hi(v.y), bf16hi(v.z), bf16hi(v.w)};
        *(ushort4*)(zhF + fragAddr(m, c0)) = hv;    // c0 4-aligned, 8B-aligned slot
    }
}

// ---------------- Kernel C: bf16x1 32x32x16-MFMA screen, coalesced frag loads ----
// All operand loads are wave-uniform base + l*8 ushorts = contiguous 1KB --
// zero gathers. Same per-lane values as r18's verified version (screen bitwise
// identical); D col=lane&31 [m74/m101-verified]; group max permutation-invariant.
__global__ __launch_bounds__(256, 4)
void k_simmax(const ushort_t* __restrict__ zhF, const ushort_t* __restrict__ chF,
              float* __restrict__ gmax) {
    int wv = threadIdx.x >> 6, l = threadIdx.x & 63;
    int m0 = (blockIdx.x * 4 + wv) * 64;
    int p0 = blockIdx.y * PCH;
    int ln = l & 31;

    bf16x8 bh[2][4];
    #pragma unroll
    for (int mt = 0; mt < 2; ++mt) {
        const ushort_t* zb = zhF + ((size_t)(m0 >> 5) + mt) * 2048;
        #pragma unroll
        for (int st = 0; st < 4; ++st)
            bh[mt][st] = *(const bf16x8*)(zb + st * 512 + l * 8);
    }

    for (int g = 0; g < PCH / GRP; ++g) {           // 16 groups of 32 p
        const ushort_t* ab = chF + ((size_t)(p0 >> 5) + g) * 2048;
        bf16x8 a0 = *(const bf16x8*)(ab + 0 * 512 + l * 8);
        bf16x8 a1 = *(const bf16x8*)(ab + 1 * 512 + l * 8);
        bf16x8 a2 = *(const bf16x8*)(ab + 2 * 512 + l * 8);
        bf16x8 a3 = *(const bf16x8*)(ab + 3 * 512 + l * 8);

        #pragma unroll
        for (int mt = 0; mt < 2; ++mt) {
            f32x16 acc = {0.f, 0.f, 0.f, 0.f, 0.f, 0.f, 0.f, 0.f,
                          0.f, 0.f, 0.f, 0.f, 0.f, 0.f, 0.f, 0.f};
            acc = __builtin_amdgcn_mfma_f32_32x32x16_bf16(a0, bh[mt][0], acc, 0, 0, 0);
            acc = __builtin_amdgcn_mfma_f32_32x32x16_bf16(a1, bh[mt][1], acc, 0, 0, 0);
            acc = __builtin_amdgcn_mfma_f32_32x32x16_bf16(a2, bh[mt][2], acc, 0, 0, 0);
            acc = __builtin_amdgcn_mfma_f32_32x32x16_bf16(a3, bh[mt][3], acc, 0, 0, 0);
            float v0 = fmaxf(acc[0], acc[1]),   v1 = fmaxf(acc[2], acc[3]);
            float v2 = fmaxf(acc[4], acc[5]),   v3 = fmaxf(acc[6], acc[7]);
            float v4 = fmaxf(acc[8], acc[9]),   v5 = fmaxf(acc[10], acc[11]);
            float v6 = fmaxf(acc[12], acc[13]), v7 = fmaxf(acc[14], acc[15]);
            float v = fmaxf(fmaxf(fmaxf(v0, v1), fmaxf(v2, v3)),
                            fmaxf(fmaxf(v4, v5), fmaxf(v6, v7)));
            v = fmaxf(v, __shfl_xor(v, 32, 64));
            if (l < 32)
                gmax[(size_t)(blockIdx.y * (PCH / GRP) + g) * M_TOT
                     + m0 + mt * 32 + ln] = v;
        }
    }
}

// ---------------- Kernel C2: per-row pick + fused loss partial ----------
__global__ __launch_bounds__(256)
void k_pick(const float* __restrict__ gmax, const float* __restrict__ zn,
            const float* __restrict__ cn, int* __restrict__ idx_i,
            float* __restrict__ idx_f, float* __restrict__ lossp) {
    int wv = threadIdx.x >> 6, l = threadIdx.x & 63;
    int m = blockIdx.x * 4 + wv;            // one wave per row

    float gv[4];
    #pragma unroll
    for (int b = 0; b < 4; ++b)
        gv[b] = gmax[(size_t)(b * 64 + l) * M_TOT + m];
    float rm = fmaxf(fmaxf(gv[0], gv[1]), fmaxf(gv[2], gv[3]));
    #pragma unroll
    for (int o = 32; o; o >>= 1) rm = fmaxf(rm, __shfl_xor(rm, o, 64));
    float thr = rm - MARG;

    float zr[32];
    {
        const float4* zp = (const float4*)(zn + (size_t)m * C_DIM + (l >> 5) * 32);
        #pragma unroll
        for (int q = 0; q < 8; ++q) {
            float4 v = zp[q];
            zr[4 * q] = v.x; zr[4 * q + 1] = v.y;
            zr[4 * q + 2] = v.z; zr[4 * q + 3] = v.w;
        }
    }

    float bv = NEG_BIG; int bp = P_DIM;
    #pragma unroll
    for (int b = 0; b < 4; ++b) {           // ascending batches -> ascending groups
        unsigned long long mask = __ballot(gv[b] >= thr);
        while (mask) {
            int j = __ffsll((unsigned long long)mask) - 1;
            mask &= mask - 1;               // ascending j within batch
            int g = b * 64 + j;
            int p = g * GRP + (l & 31);
            const float4* cp = (const float4*)(cn + (size_t)p * C_DIM + (l >> 5) * 32);
            float a0 = 0.f, a1 = 0.f, a2 = 0.f, a3 = 0.f;
            #pragma unroll
            for (int q = 0; q < 8; ++q) {
                float4 w = cp[q];
                a0 = fmaf(w.x, zr[4 * q + 0], a0);
                a1 = fmaf(w.y, zr[4 * q + 1], a1);
                a2 = fmaf(w.z, zr[4 * q + 2], a2);
                a3 = fmaf(w.w, zr[4 * q + 3], a3);
            }
            float s = (a0 + a1) + (a2 + a3);
            s += __shfl_xor(s, 32, 64);     // combine halves: full dot in both lanes
            if (s > bv || (s == bv && p < bp)) { bv = s; bp = p; }
        }
    }
    #pragma unroll
    for (int o = 32; o; o >>= 1) {
        float ov = __shfl_xor(bv, o, 64);
        int   op = __shfl_xor(bp, o, 64);
        if (ov > bv || (ov == bv && op < bp)) { bv = ov; bp = op; }
    }
    if (l == 0) { idx_i[m] = bp; idx_f[m] = (float)bp; }

    // fused loss partial: sum (zn - cn[bp])^2 over the row (bp wave-uniform)
    {
        const float4* cp = (const float4*)(cn + (size_t)bp * C_DIM + (l >> 5) * 32);
        float d2 = 0.f;
        #pragma unroll
        for (int q = 0; q < 8; ++q) {
            float4 w = cp[q];
            float dx = zr[4 * q + 0] - w.x; d2 = fmaf(dx, dx, d2);
            float dy = zr[4 * q + 1] - w.y; d2 = fmaf(dy, dy, d2);
            float dz = zr[4 * q + 2] - w.z; d2 = fmaf(dz, dz, d2);
            float dw = zr[4 * q + 3] - w.w; d2 = fmaf(dw, dw, d2);
        }
        d2 += __shfl_xor(d2, 32, 64);
        if (l == 0) lossp[m] = d2;
    }
}

// ---------------- Kernel D (merged with loss-final): out + loss reduce ----------
#define D_ROWS 128
#define D_BLKS (M_TOT / D_ROWS * (F_DIM / 64))      // 1536
__global__ void k_out(const int* __restrict__ idx, const float* __restrict__ cn,
                      const float* __restrict__ wT, float* __restrict__ out,
                      const float* __restrict__ lossp, float* __restrict__ loss_out) {
    __shared__ float sh[256];
    int bx = blockIdx.x;
    if (bx >= D_BLKS) {
        float s = 0.f;
        for (int i = threadIdx.x; i < M_TOT; i += 256) s += lossp[i];
        sh[threadIdx.x] = s;
        __syncthreads();
        for (int o = 128; o; o >>= 1) {
            if (threadIdx.x < o) sh[threadIdx.x] += sh[threadIdx.x + o];
            __syncthreads();
        }
        if (threadIdx.x == 0)
            loss_out[0] = 1.25f * sh[0] / (float)(M_TOT * C_DIM);
        return;
    }

    int wv = threadIdx.x >> 6, lane = threadIdx.x & 63;
    int f  = (bx >> 7) * 64 + lane;     // bx/128 in 0..11
    int m0 = (bx & 127) * D_ROWS + wv * 32;

    float wcol[64];
    #pragma unroll
    for (int c = 0; c < 64; ++c) wcol[c] = wT[(size_t)c * F_DIM + f];

    #pragma unroll 4
    for (int r = 0; r < 32; ++r) {
        int m = __builtin_amdgcn_readfirstlane(m0 + r);
        const float4* cp = (const float4*)(cn + (size_t)idx[m] * C_DIM);
        float a0 = 0.f, a1 = 0.f, a2 = 0.f, a3 = 0.f;
        #pragma unroll
        for (int j = 0; j < 16; ++j) {
            float4 cv = cp[j];
            a0 = fmaf(cv.x, wcol[4 * j + 0], a0);
            a1 = fmaf(cv.y, wcol[4 * j + 1], a1);
            a2 = fmaf(cv.z, wcol[4 * j + 2], a2);
            a3 = fmaf(cv.w, wcol[4 * j + 3], a3);
        }
        out[(size_t)m * F_DIM + f] = (a0 + a1) + (a2 + a3);
    }
}

extern "C" void kernel_launch(void* const* d_in, const int* in_sizes, int n_in,
                              void* d_out, int out_size, void* d_ws, size_t ws_size,
                              hipStream_t stream) {
    const float* z     = (const float*)d_in[0];
    const float* w_in  = (const float*)d_in[1];
    const float* w_out = (const float*)d_in[2];
    const float* cb    = (const float*)d_in[3];

    float* out    = (float*)d_out;
    float* lossO  = out + (size_t)M_TOT * F_DIM;
    float* idxO   = lossO + 1;
    // gmax (16.8 MB) lives in the d_out 'out' region: written by k_simmax, read
    // by k_pick, then fully overwritten by k_out afterwards (stream-ordered).
    float* gmax   = out;

    float* ws    = (float*)d_ws;                          // total ~9.4 MB
    float* cn    = ws;                                    // 524288 f   (2 MB)
    float* zn    = cn + (size_t)P_DIM * C_DIM;            // 1048576 f  (4 MB)
    float* wT    = zn + (size_t)M_TOT * C_DIM;            // 49152 f
    float* lossp = wT + (size_t)C_DIM * F_DIM;            // 16384 f
    int*   idxi  = (int*)(lossp + M_TOT);                 // 16384 i
    ushort_t* zhF = (ushort_t*)(idxi + M_TOT);            // 1048576 us (2 MB)
    ushort_t* chF = zhF + (size_t)M_TOT * C_DIM;          // 524288 us  (1 MB)

    int projGrid = PROJ_BLKS + P_DIM / 4 + (C_DIM * F_DIM) / 256;   // 512+2048+192
    k_proj<<<projGrid, 256, 0, stream>>>(z, w_in, zn, zhF, cb, cn, chF, w_out, wT);

    dim3 gC(M_TOT / 256, NCH);
    k_simmax<<<gC, 256, 0, stream>>>(zhF, chF, gmax);
    k_pick<<<M_TOT / 4, 256, 0, stream>>>(gmax, zn, cn, idxi, idxO, lossp);

    k_out<<<D_BLKS + 1, 256, 0, stream>>>(idxi, cn, wT, out, lossp, lossO);
}

// Round 21
// 139.273 us; speedup vs baseline: 1.3853x; 1.1113x over previous
//
#include <hip/hip_runtime.h>
#include <hip/hip_bf16.h>
#include <math.h>

#define M_TOT   16384      // B*N = 4*4096
#define F_DIM   768
#define C_DIM   64
#define P_DIM   8192
#define EPSN    1e-12f
#define NEG_BIG (-3.402823466e38f)
#define NCH     16
#define PCH     (P_DIM / NCH)   // 512
#define GRP     32
#define NGRP    (P_DIM / GRP)   // 256
#define MARG    1e-2f           // >= 2 * 4e-3 hard bf16x1 screen error bound

typedef __attribute__((ext_vector_type(8))) short bf16x8;
typedef __attribute__((ext_vector_type(4))) float f32x4;
typedef __attribute__((ext_vector_type(16))) float f32x16;
typedef unsigned short ushort_t;
typedef const __attribute__((address_space(1))) void* gas1_t;
typedef __attribute__((address_space(3))) void* las3_t;

__device__ inline ushort_t bf16hi(float v) {
    __hip_bfloat16 hb = __float2bfloat16(v);
    return *reinterpret_cast<ushort_t*>(&hb);
}

// MFMA-fragment-order layout for the bf16 screen operands (r20, proven):
//   frag[(row>>5)*8 + (k>>4)*2 + ((k>>3)&1)] [ (row&31)*8 + (k&7) ]
__device__ inline size_t fragAddr(int row, int k) {
    return ((size_t)(row >> 5) * 8 + (k >> 4) * 2 + ((k >> 3) & 1)) * 256
         + (row & 31) * 8 + (k & 7);
}

// ---------------- Kernel B (merged with prep): proj + cb-norm + wout-T ----------
#define PBM 32
#define PKC 64
#define PROJ_BLKS (M_TOT / PBM)             // 512
__global__ __launch_bounds__(256)
void k_proj(const float* __restrict__ z, const float* __restrict__ w_in,
            float* __restrict__ zn, ushort_t* __restrict__ zhF,
            const float* __restrict__ cb, float* __restrict__ cn,
            ushort_t* __restrict__ chF, const float* __restrict__ w_out,
            float* __restrict__ wT) {
    __shared__ float lw[2][C_DIM * PKC];   // 2 x 16 KB  [c][slot*4]

    const int bx = blockIdx.x;
    if (bx >= PROJ_BLKS) {
        int pb = bx - PROJ_BLKS;
        if (pb < P_DIM / 4) {
            int wv = threadIdx.x >> 6, lane = threadIdx.x & 63;
            int row = pb * 4 + wv;
            float v = cb[(size_t)row * C_DIM + lane];
            float s = v * v;
            #pragma unroll
            for (int o = 32; o; o >>= 1) s += __shfl_xor(s, o, 64);
            float inv = 1.0f / fmaxf(sqrtf(s), EPSN);
            float nv = v * inv;
            cn[(size_t)row * C_DIM + lane] = nv;
            chF[fragAddr(row, lane)] = bf16hi(nv);
        } else {
            int i = (pb - P_DIM / 4) * 256 + threadIdx.x;   // 49152 total
            int f = i >> 6, c = i & 63;
            wT[(size_t)c * F_DIM + f] = w_out[i];
        }
        return;
    }

    const int t  = threadIdx.x;
    const int m0 = bx * PBM;
    const int r0 = (t >> 4) * 2;        // rows r0..r0+1  (t>>4 in 0..15)
    const int c0 = (t & 15) * 4;        // cols c0..c0+3
    const int wswz = t & 15;            // == ((c0+cj)>>2)&15 for cj<4

    const float* zrow[2];
    #pragma unroll
    for (int ri = 0; ri < 2; ++ri)
        zrow[ri] = z + (size_t)(m0 + r0 + ri) * F_DIM;

    float acc[2][4];
    #pragma unroll
    for (int i = 0; i < 2; ++i)
        #pragma unroll
        for (int j = 0; j < 4; ++j) acc[i][j] = 0.0f;

    // stage w chunk 0 into buffer 0 (1024 float4 over 256 thr = 4 each)
    #pragma unroll
    for (int i = 0; i < 4; ++i) {
        int f4 = i * 256 + t; int c = f4 >> 4, s4 = f4 & 15;
        __builtin_amdgcn_global_load_lds(
            (gas1_t)(w_in + (size_t)c * F_DIM + (s4 ^ ((c >> 2) & 15)) * 4),
            (las3_t)(&lw[0][f4 * 4]), 16, 0, 0);
    }
    __syncthreads();

    int cur = 0;
    for (int k0 = 0; k0 < F_DIM; k0 += PKC) {       // 12 chunks
        if (k0 + PKC < F_DIM) {                     // issue next-chunk DMA first
            int nxt = cur ^ 1;
            #pragma unroll
            for (int i = 0; i < 4; ++i) {
                int f4 = i * 256 + t; int c = f4 >> 4, s4 = f4 & 15;
                __builtin_amdgcn_global_load_lds(
                    (gas1_t)(w_in + (size_t)c * F_DIM + k0 + PKC
                             + (s4 ^ ((c >> 2) & 15)) * 4),
                    (las3_t)(&lw[nxt][f4 * 4]), 16, 0, 0);
            }
        }

        const float* lwb = lw[cur];
        #pragma unroll
        for (int kq = 0; kq < 16; ++kq) {
            float4 zf[2], wf[4];
            int wo = (kq ^ wswz) * 4;
            #pragma unroll
            for (int ri = 0; ri < 2; ++ri)
                zf[ri] = *(const float4*)(zrow[ri] + k0 + kq * 4);
            #pragma unroll
            for (int cj = 0; cj < 4; ++cj)
                wf[cj] = *(const float4*)(lwb + (c0 + cj) * PKC + wo);
            #pragma unroll
            for (int ri = 0; ri < 2; ++ri)
                #pragma unroll
                for (int cj = 0; cj < 4; ++cj) {
                    acc[ri][cj] = fmaf(zf[ri].x, wf[cj].x, acc[ri][cj]);
                    acc[ri][cj] = fmaf(zf[ri].y, wf[cj].y, acc[ri][cj]);
                    acc[ri][cj] = fmaf(zf[ri].z, wf[cj].z, acc[ri][cj]);
                    acc[ri][cj] = fmaf(zf[ri].w, wf[cj].w, acc[ri][cj]);
                }
        }
        __syncthreads();    // vmcnt(0)+barrier: next w chunk landed, cur free
        cur ^= 1;
    }

    // ---- epilogue: row-norm; zn unchanged (bitwise), zh scattered to frag order
    #pragma unroll
    for (int ri = 0; ri < 2; ++ri) {
        float s = acc[ri][0] * acc[ri][0] + acc[ri][1] * acc[ri][1]
                + acc[ri][2] * acc[ri][2] + acc[ri][3] * acc[ri][3];
        #pragma unroll
        for (int o = 1; o < 16; o <<= 1) s += __shfl_xor(s, o, 64);
        float inv = 1.0f / fmaxf(sqrtf(s), EPSN);
        float4 v;
        v.x = acc[ri][0] * inv; v.y = acc[ri][1] * inv;
        v.z = acc[ri][2] * inv; v.w = acc[ri][3] * inv;
        int m = m0 + r0 + ri;
        *(float4*)(zn + (size_t)m * C_DIM + c0) = v;
        ushort4 hv = {bf16hi(v.x), bf16hi(v.y), bf16hi(v.z), bf16hi(v.w)};
        *(ushort4*)(zhF + fragAddr(m, c0)) = hv;
    }
}

// ---------------- Kernel C: bf16x1 32x32x16-MFMA screen, coalesced frag loads ----
// gmaxT layout [M_TOT][NGRP]: per-lane group maxima accumulated in registers
// (g-loop fully unrolled -> static indices), lane l owns row m0+l, written as
// 4x float4 at the end. Values bitwise-identical to r20; only addresses change.
__global__ __launch_bounds__(256, 4)
void k_simmax(const ushort_t* __restrict__ zhF, const ushort_t* __restrict__ chF,
              float* __restrict__ gmaxT) {
    int wv = threadIdx.x >> 6, l = threadIdx.x & 63;
    int m0 = (blockIdx.x * 4 + wv) * 64;
    int p0 = blockIdx.y * PCH;

    bf16x8 bh[2][4];
    #pragma unroll
    for (int mt = 0; mt < 2; ++mt) {
        const ushort_t* zb = zhF + ((size_t)(m0 >> 5) + mt) * 2048;
        #pragma unroll
        for (int st = 0; st < 4; ++st)
            bh[mt][st] = *(const bf16x8*)(zb + st * 512 + l * 8);
    }

    float sel[16];      // per-lane row (m0+l) group maxima for this chunk

    #pragma unroll
    for (int g = 0; g < PCH / GRP; ++g) {           // 16 groups of 32 p
        const ushort_t* ab = chF + ((size_t)(p0 >> 5) + g) * 2048;
        bf16x8 a0 = *(const bf16x8*)(ab + 0 * 512 + l * 8);
        bf16x8 a1 = *(const bf16x8*)(ab + 1 * 512 + l * 8);
        bf16x8 a2 = *(const bf16x8*)(ab + 2 * 512 + l * 8);
        bf16x8 a3 = *(const bf16x8*)(ab + 3 * 512 + l * 8);

        float gm[2];
        #pragma unroll
        for (int mt = 0; mt < 2; ++mt) {
            f32x16 acc = {0.f, 0.f, 0.f, 0.f, 0.f, 0.f, 0.f, 0.f,
                          0.f, 0.f, 0.f, 0.f, 0.f, 0.f, 0.f, 0.f};
            acc = __builtin_amdgcn_mfma_f32_32x32x16_bf16(a0, bh[mt][0], acc, 0, 0, 0);
            acc = __builtin_amdgcn_mfma_f32_32x32x16_bf16(a1, bh[mt][1], acc, 0, 0, 0);
            acc = __builtin_amdgcn_mfma_f32_32x32x16_bf16(a2, bh[mt][2], acc, 0, 0, 0);
            acc = __builtin_amdgcn_mfma_f32_32x32x16_bf16(a3, bh[mt][3], acc, 0, 0, 0);
            float v0 = fmaxf(acc[0], acc[1]),   v1 = fmaxf(acc[2], acc[3]);
            float v2 = fmaxf(acc[4], acc[5]),   v3 = fmaxf(acc[6], acc[7]);
            float v4 = fmaxf(acc[8], acc[9]),   v5 = fmaxf(acc[10], acc[11]);
            float v6 = fmaxf(acc[12], acc[13]), v7 = fmaxf(acc[14], acc[15]);
            float v = fmaxf(fmaxf(fmaxf(v0, v1), fmaxf(v2, v3)),
                            fmaxf(fmaxf(v4, v5), fmaxf(v6, v7)));
            gm[mt] = fmaxf(v, __shfl_xor(v, 32, 64));   // both halves hold max
        }
        sel[g] = (l < 32) ? gm[0] : gm[1];  // lane l owns row m0 + l
    }

    // write row (m0+l)'s 16 chunk-group maxima: 4x float4, 64B per lane
    float* dst = gmaxT + (size_t)(m0 + l) * NGRP + blockIdx.y * (PCH / GRP);
    #pragma unroll
    for (int q = 0; q < 4; ++q) {
        float4 st = {sel[4 * q], sel[4 * q + 1], sel[4 * q + 2], sel[4 * q + 3]};
        *(float4*)(dst + 4 * q) = st;
    }
}

// ---------------- Kernel C2: per-row pick + fused loss partial ----------
// gmaxT reads now fully coalesced: lane l reads gmaxT[m*256 + b*64 + l].
__global__ __launch_bounds__(256)
void k_pick(const float* __restrict__ gmaxT, const float* __restrict__ zn,
            const float* __restrict__ cn, int* __restrict__ idx_i,
            float* __restrict__ idx_f, float* __restrict__ lossp) {
    int wv = threadIdx.x >> 6, l = threadIdx.x & 63;
    int m = blockIdx.x * 4 + wv;            // one wave per row

    float gv[4];
    #pragma unroll
    for (int b = 0; b < 4; ++b)
        gv[b] = gmaxT[(size_t)m * NGRP + b * 64 + l];
    float rm = fmaxf(fmaxf(gv[0], gv[1]), fmaxf(gv[2], gv[3]));
    #pragma unroll
    for (int o = 32; o; o >>= 1) rm = fmaxf(rm, __shfl_xor(rm, o, 64));
    float thr = rm - MARG;

    float zr[32];
    {
        const float4* zp = (const float4*)(zn + (size_t)m * C_DIM + (l >> 5) * 32);
        #pragma unroll
        for (int q = 0; q < 8; ++q) {
            float4 v = zp[q];
            zr[4 * q] = v.x; zr[4 * q + 1] = v.y;
            zr[4 * q + 2] = v.z; zr[4 * q + 3] = v.w;
        }
    }

    float bv = NEG_BIG; int bp = P_DIM;
    #pragma unroll
    for (int b = 0; b < 4; ++b) {           // ascending batches -> ascending groups
        unsigned long long mask = __ballot(gv[b] >= thr);
        while (mask) {
            int j = __ffsll((unsigned long long)mask) - 1;
            mask &= mask - 1;               // ascending j within batch
            int g = b * 64 + j;
            int p = g * GRP + (l & 31);
            const float4* cp = (const float4*)(cn + (size_t)p * C_DIM + (l >> 5) * 32);
            float a0 = 0.f, a1 = 0.f, a2 = 0.f, a3 = 0.f;
            #pragma unroll
            for (int q = 0; q < 8; ++q) {
                float4 w = cp[q];
                a0 = fmaf(w.x, zr[4 * q + 0], a0);
                a1 = fmaf(w.y, zr[4 * q + 1], a1);
                a2 = fmaf(w.z, zr[4 * q + 2], a2);
                a3 = fmaf(w.w, zr[4 * q + 3], a3);
            }
            float s = (a0 + a1) + (a2 + a3);
            s += __shfl_xor(s, 32, 64);     // combine halves: full dot in both lanes
            if (s > bv || (s == bv && p < bp)) { bv = s; bp = p; }
        }
    }
    #pragma unroll
    for (int o = 32; o; o >>= 1) {
        float ov = __shfl_xor(bv, o, 64);
        int   op = __shfl_xor(bp, o, 64);
        if (ov > bv || (ov == bv && op < bp)) { bv = ov; bp = op; }
    }
    if (l == 0) { idx_i[m] = bp; idx_f[m] = (float)bp; }

    // fused loss partial: sum (zn - cn[bp])^2 over the row (bp wave-uniform)
    {
        const float4* cp = (const float4*)(cn + (size_t)bp * C_DIM + (l >> 5) * 32);
        float d2 = 0.f;
        #pragma unroll
        for (int q = 0; q < 8; ++q) {
            float4 w = cp[q];
            float dx = zr[4 * q + 0] - w.x; d2 = fmaf(dx, dx, d2);
            float dy = zr[4 * q + 1] - w.y; d2 = fmaf(dy, dy, d2);
            float dz = zr[4 * q + 2] - w.z; d2 = fmaf(dz, dz, d2);
            float dw = zr[4 * q + 3] - w.w; d2 = fmaf(dw, dw, d2);
        }
        d2 += __shfl_xor(d2, 32, 64);
        if (l == 0) lossp[m] = d2;
    }
}

// ---------------- Kernel D (merged with loss-final): out + loss reduce ----------
#define D_ROWS 128
#define D_BLKS (M_TOT / D_ROWS * (F_DIM / 64))      // 1536
__global__ void k_out(const int* __restrict__ idx, const float* __restrict__ cn,
                      const float* __restrict__ wT, float* __restrict__ out,
                      const float* __restrict__ lossp, float* __restrict__ loss_out) {
    __shared__ float sh[256];
    int bx = blockIdx.x;
    if (bx >= D_BLKS) {
        float s = 0.f;
        for (int i = threadIdx.x; i < M_TOT; i += 256) s += lossp[i];
        sh[threadIdx.x] = s;
        __syncthreads();
        for (int o = 128; o; o >>= 1) {
            if (threadIdx.x < o) sh[threadIdx.x] += sh[threadIdx.x + o];
            __syncthreads();
        }
        if (threadIdx.x == 0)
            loss_out[0] = 1.25f * sh[0] / (float)(M_TOT * C_DIM);
        return;
    }

    int wv = threadIdx.x >> 6, lane = threadIdx.x & 63;
    int f  = (bx >> 7) * 64 + lane;     // bx/128 in 0..11
    int m0 = (bx & 127) * D_ROWS + wv * 32;

    float wcol[64];
    #pragma unroll
    for (int c = 0; c < 64; ++c) wcol[c] = wT[(size_t)c * F_DIM + f];

    #pragma unroll 4
    for (int r = 0; r < 32; ++r) {
        int m = __builtin_amdgcn_readfirstlane(m0 + r);
        const float4* cp = (const float4*)(cn + (size_t)idx[m] * C_DIM);
        float a0 = 0.f, a1 = 0.f, a2 = 0.f, a3 = 0.f;
        #pragma unroll
        for (int j = 0; j < 16; ++j) {
            float4 cv = cp[j];
            a0 = fmaf(cv.x, wcol[4 * j + 0], a0);
            a1 = fmaf(cv.y, wcol[4 * j + 1], a1);
            a2 = fmaf(cv.z, wcol[4 * j + 2], a2);
            a3 = fmaf(cv.w, wcol[4 * j + 3], a3);
        }
        out[(size_t)m * F_DIM + f] = (a0 + a1) + (a2 + a3);
    }
}

extern "C" void kernel_launch(void* const* d_in, const int* in_sizes, int n_in,
                              void* d_out, int out_size, void* d_ws, size_t ws_size,
                              hipStream_t stream) {
    const float* z     = (const float*)d_in[0];
    const float* w_in  = (const float*)d_in[1];
    const float* w_out = (const float*)d_in[2];
    const float* cb    = (const float*)d_in[3];

    float* out    = (float*)d_out;
    float* lossO  = out + (size_t)M_TOT * F_DIM;
    float* idxO   = lossO + 1;
    // gmaxT (16.8 MB, [M_TOT][NGRP]) lives in the d_out 'out' region: written by
    // k_simmax, read by k_pick, then fully overwritten by k_out (stream-ordered).
    float* gmaxT  = out;

    float* ws    = (float*)d_ws;                          // total ~9.4 MB
    float* cn    = ws;                                    // 524288 f   (2 MB)
    float* zn    = cn + (size_t)P_DIM * C_DIM;            // 1048576 f  (4 MB)
    float* wT    = zn + (size_t)M_TOT * C_DIM;            // 49152 f
    float* lossp = wT + (size_t)C_DIM * F_DIM;            // 16384 f
    int*   idxi  = (int*)(lossp + M_TOT);                 // 16384 i
    ushort_t* zhF = (ushort_t*)(idxi + M_TOT);            // 1048576 us (2 MB)
    ushort_t* chF = zhF + (size_t)M_TOT * C_DIM;          // 524288 us  (1 MB)

    int projGrid = PROJ_BLKS + P_DIM / 4 + (C_DIM * F_DIM) / 256;   // 512+2048+192
    k_proj<<<projGrid, 256, 0, stream>>>(z, w_in, zn, zhF, cb, cn, chF, w_out, wT);

    dim3 gC(M_TOT / 256, NCH);
    k_simmax<<<gC, 256, 0, stream>>>(zhF, chF, gmaxT);
    k_pick<<<M_TOT / 4, 256, 0, stream>>>(gmaxT, zn, cn, idxi, idxO, lossp);

    k_out<<<D_BLKS + 1, 256, 0, stream>>>(idxi, cn, wT, out, lossp, lossO);
}

// Round 22
// 129.648 us; speedup vs baseline: 1.4882x; 1.0742x over previous
//
#include <hip/hip_runtime.h>
#include <hip/hip_bf16.h>
#include <math.h>

#define M_TOT   16384      // B*N = 4*4096
#define F_DIM   768
#define C_DIM   64
#define P_DIM   8192
#define EPSN    1e-12f
#define NEG_BIG (-3.402823466e38f)
#define NCH     16
#define PCH     (P_DIM / NCH)   // 512
#define GRP     32
#define NGRP    (P_DIM / GRP)   // 256
#define MARG    1e-2f           // >= 2 * 4e-3 hard bf16x1 screen error bound

typedef __attribute__((ext_vector_type(8))) short bf16x8;
typedef __attribute__((ext_vector_type(4))) float f32x4;
typedef __attribute__((ext_vector_type(16))) float f32x16;
typedef unsigned short ushort_t;
typedef const __attribute__((address_space(1))) void* gas1_t;
typedef __attribute__((address_space(3))) void* las3_t;

__device__ inline ushort_t bf16hi(float v) {
    __hip_bfloat16 hb = __float2bfloat16(v);
    return *reinterpret_cast<ushort_t*>(&hb);
}

// MFMA-fragment-order layout for the bf16 screen operands (r20, proven):
//   frag[(row>>5)*8 + (k>>4)*2 + ((k>>3)&1)] [ (row&31)*8 + (k&7) ]
__device__ inline size_t fragAddr(int row, int k) {
    return ((size_t)(row >> 5) * 8 + (k >> 4) * 2 + ((k >> 3) & 1)) * 256
         + (row & 31) * 8 + (k & 7);
}

// Pick-ordered fp32 codebook copy: cnG[g][j][h][c], addr = g*2048 + j*64 + h*32 + c
// (g = code>>5, c = code&31, k = h*32 + j). k_pick's rescan then reads 64
// consecutive floats per wave-instruction (lane l at offset j*64 + l).
__device__ inline size_t pickAddr(int row, int k) {
    return (size_t)(row >> 5) * 2048 + (k & 31) * 64 + (k >> 5) * 32 + (row & 31);
}

// ---------------- Kernel B (merged with prep): proj + cb-norm + wout-T ----------
#define PBM 32
#define PKC 64
#define PROJ_BLKS (M_TOT / PBM)             // 512
__global__ __launch_bounds__(256)
void k_proj(const float* __restrict__ z, const float* __restrict__ w_in,
            float* __restrict__ zn, ushort_t* __restrict__ zhF,
            const float* __restrict__ cb, float* __restrict__ cn,
            ushort_t* __restrict__ chF, float* __restrict__ cnG,
            const float* __restrict__ w_out, float* __restrict__ wT) {
    __shared__ float lw[2][C_DIM * PKC];   // 2 x 16 KB  [c][slot*4]

    const int bx = blockIdx.x;
    if (bx >= PROJ_BLKS) {
        int pb = bx - PROJ_BLKS;
        if (pb < P_DIM / 4) {
            int wv = threadIdx.x >> 6, lane = threadIdx.x & 63;
            int row = pb * 4 + wv;
            float v = cb[(size_t)row * C_DIM + lane];
            float s = v * v;
            #pragma unroll
            for (int o = 32; o; o >>= 1) s += __shfl_xor(s, o, 64);
            float inv = 1.0f / fmaxf(sqrtf(s), EPSN);
            float nv = v * inv;
            cn[(size_t)row * C_DIM + lane] = nv;
            chF[fragAddr(row, lane)] = bf16hi(nv);
            cnG[pickAddr(row, lane)] = nv;
        } else {
            int i = (pb - P_DIM / 4) * 256 + threadIdx.x;   // 49152 total
            int f = i >> 6, c = i & 63;
            wT[(size_t)c * F_DIM + f] = w_out[i];
        }
        return;
    }

    const int t  = threadIdx.x;
    const int m0 = bx * PBM;
    const int r0 = (t >> 4) * 2;        // rows r0..r0+1  (t>>4 in 0..15)
    const int c0 = (t & 15) * 4;        // cols c0..c0+3
    const int wswz = t & 15;            // == ((c0+cj)>>2)&15 for cj<4

    const float* zrow[2];
    #pragma unroll
    for (int ri = 0; ri < 2; ++ri)
        zrow[ri] = z + (size_t)(m0 + r0 + ri) * F_DIM;

    float acc[2][4];
    #pragma unroll
    for (int i = 0; i < 2; ++i)
        #pragma unroll
        for (int j = 0; j < 4; ++j) acc[i][j] = 0.0f;

    // stage w chunk 0 into buffer 0 (1024 float4 over 256 thr = 4 each)
    #pragma unroll
    for (int i = 0; i < 4; ++i) {
        int f4 = i * 256 + t; int c = f4 >> 4, s4 = f4 & 15;
        __builtin_amdgcn_global_load_lds(
            (gas1_t)(w_in + (size_t)c * F_DIM + (s4 ^ ((c >> 2) & 15)) * 4),
            (las3_t)(&lw[0][f4 * 4]), 16, 0, 0);
    }
    __syncthreads();

    int cur = 0;
    for (int k0 = 0; k0 < F_DIM; k0 += PKC) {       // 12 chunks
        if (k0 + PKC < F_DIM) {                     // issue next-chunk DMA first
            int nxt = cur ^ 1;
            #pragma unroll
            for (int i = 0; i < 4; ++i) {
                int f4 = i * 256 + t; int c = f4 >> 4, s4 = f4 & 15;
                __builtin_amdgcn_global_load_lds(
                    (gas1_t)(w_in + (size_t)c * F_DIM + k0 + PKC
                             + (s4 ^ ((c >> 2) & 15)) * 4),
                    (las3_t)(&lw[nxt][f4 * 4]), 16, 0, 0);
            }
        }

        const float* lwb = lw[cur];
        #pragma unroll
        for (int kq = 0; kq < 16; ++kq) {
            float4 zf[2], wf[4];
            int wo = (kq ^ wswz) * 4;
            #pragma unroll
            for (int ri = 0; ri < 2; ++ri)
                zf[ri] = *(const float4*)(zrow[ri] + k0 + kq * 4);
            #pragma unroll
            for (int cj = 0; cj < 4; ++cj)
                wf[cj] = *(const float4*)(lwb + (c0 + cj) * PKC + wo);
            #pragma unroll
            for (int ri = 0; ri < 2; ++ri)
                #pragma unroll
                for (int cj = 0; cj < 4; ++cj) {
                    acc[ri][cj] = fmaf(zf[ri].x, wf[cj].x, acc[ri][cj]);
                    acc[ri][cj] = fmaf(zf[ri].y, wf[cj].y, acc[ri][cj]);
                    acc[ri][cj] = fmaf(zf[ri].z, wf[cj].z, acc[ri][cj]);
                    acc[ri][cj] = fmaf(zf[ri].w, wf[cj].w, acc[ri][cj]);
                }
        }
        __syncthreads();    // vmcnt(0)+barrier: next w chunk landed, cur free
        cur ^= 1;
    }

    // ---- epilogue: row-norm; zn unchanged (bitwise), zh scattered to frag order
    #pragma unroll
    for (int ri = 0; ri < 2; ++ri) {
        float s = acc[ri][0] * acc[ri][0] + acc[ri][1] * acc[ri][1]
                + acc[ri][2] * acc[ri][2] + acc[ri][3] * acc[ri][3];
        #pragma unroll
        for (int o = 1; o < 16; o <<= 1) s += __shfl_xor(s, o, 64);
        float inv = 1.0f / fmaxf(sqrtf(s), EPSN);
        float4 v;
        v.x = acc[ri][0] * inv; v.y = acc[ri][1] * inv;
        v.z = acc[ri][2] * inv; v.w = acc[ri][3] * inv;
        int m = m0 + r0 + ri;
        *(float4*)(zn + (size_t)m * C_DIM + c0) = v;
        ushort4 hv = {bf16hi(v.x), bf16hi(v.y), bf16hi(v.z), bf16hi(v.w)};
        *(ushort4*)(zhF + fragAddr(m, c0)) = hv;
    }
}

// ---------------- Kernel C: bf16x1 32x32x16-MFMA screen, coalesced frag loads ----
// r21's proven version: gmaxT[M_TOT][NGRP], per-lane register accumulation.
__global__ __launch_bounds__(256, 4)
void k_simmax(const ushort_t* __restrict__ zhF, const ushort_t* __restrict__ chF,
              float* __restrict__ gmaxT) {
    int wv = threadIdx.x >> 6, l = threadIdx.x & 63;
    int m0 = (blockIdx.x * 4 + wv) * 64;
    int p0 = blockIdx.y * PCH;

    bf16x8 bh[2][4];
    #pragma unroll
    for (int mt = 0; mt < 2; ++mt) {
        const ushort_t* zb = zhF + ((size_t)(m0 >> 5) + mt) * 2048;
        #pragma unroll
        for (int st = 0; st < 4; ++st)
            bh[mt][st] = *(const bf16x8*)(zb + st * 512 + l * 8);
    }

    float sel[16];      // per-lane row (m0+l) group maxima for this chunk

    #pragma unroll
    for (int g = 0; g < PCH / GRP; ++g) {           // 16 groups of 32 p
        const ushort_t* ab = chF + ((size_t)(p0 >> 5) + g) * 2048;
        bf16x8 a0 = *(const bf16x8*)(ab + 0 * 512 + l * 8);
        bf16x8 a1 = *(const bf16x8*)(ab + 1 * 512 + l * 8);
        bf16x8 a2 = *(const bf16x8*)(ab + 2 * 512 + l * 8);
        bf16x8 a3 = *(const bf16x8*)(ab + 3 * 512 + l * 8);

        float gm[2];
        #pragma unroll
        for (int mt = 0; mt < 2; ++mt) {
            f32x16 acc = {0.f, 0.f, 0.f, 0.f, 0.f, 0.f, 0.f, 0.f,
                          0.f, 0.f, 0.f, 0.f, 0.f, 0.f, 0.f, 0.f};
            acc = __builtin_amdgcn_mfma_f32_32x32x16_bf16(a0, bh[mt][0], acc, 0, 0, 0);
            acc = __builtin_amdgcn_mfma_f32_32x32x16_bf16(a1, bh[mt][1], acc, 0, 0, 0);
            acc = __builtin_amdgcn_mfma_f32_32x32x16_bf16(a2, bh[mt][2], acc, 0, 0, 0);
            acc = __builtin_amdgcn_mfma_f32_32x32x16_bf16(a3, bh[mt][3], acc, 0, 0, 0);
            float v0 = fmaxf(acc[0], acc[1]),   v1 = fmaxf(acc[2], acc[3]);
            float v2 = fmaxf(acc[4], acc[5]),   v3 = fmaxf(acc[6], acc[7]);
            float v4 = fmaxf(acc[8], acc[9]),   v5 = fmaxf(acc[10], acc[11]);
            float v6 = fmaxf(acc[12], acc[13]), v7 = fmaxf(acc[14], acc[15]);
            float v = fmaxf(fmaxf(fmaxf(v0, v1), fmaxf(v2, v3)),
                            fmaxf(fmaxf(v4, v5), fmaxf(v6, v7)));
            gm[mt] = fmaxf(v, __shfl_xor(v, 32, 64));   // both halves hold max
        }
        sel[g] = (l < 32) ? gm[0] : gm[1];  // lane l owns row m0 + l
    }

    float* dst = gmaxT + (size_t)(m0 + l) * NGRP + blockIdx.y * (PCH / GRP);
    #pragma unroll
    for (int q = 0; q < 4; ++q) {
        float4 st = {sel[4 * q], sel[4 * q + 1], sel[4 * q + 2], sel[4 * q + 3]};
        *(float4*)(dst + 4 * q) = st;
    }
}

// ---------------- Kernel C2: per-row pick + fused loss partial ----------
// Rescan reads cnG (pick-ordered): lane l loads cnG[g*2048 + j*64 + l] --
// 64 consecutive floats per instruction, zero gathers. Chain j%4 -> a0..a3
// reproduces the float4 version's product order exactly (s bitwise identical).
__global__ __launch_bounds__(256)
void k_pick(const float* __restrict__ gmaxT, const float* __restrict__ zn,
            const float* __restrict__ cn, const float* __restrict__ cnG,
            int* __restrict__ idx_i, float* __restrict__ idx_f,
            float* __restrict__ lossp) {
    int wv = threadIdx.x >> 6, l = threadIdx.x & 63;
    int m = blockIdx.x * 4 + wv;            // one wave per row

    float gv[4];
    #pragma unroll
    for (int b = 0; b < 4; ++b)
        gv[b] = gmaxT[(size_t)m * NGRP + b * 64 + l];
    float rm = fmaxf(fmaxf(gv[0], gv[1]), fmaxf(gv[2], gv[3]));
    #pragma unroll
    for (int o = 32; o; o >>= 1) rm = fmaxf(rm, __shfl_xor(rm, o, 64));
    float thr = rm - MARG;

    float zr[32];
    {
        const float4* zp = (const float4*)(zn + (size_t)m * C_DIM + (l >> 5) * 32);
        #pragma unroll
        for (int q = 0; q < 8; ++q) {
            float4 v = zp[q];
            zr[4 * q] = v.x; zr[4 * q + 1] = v.y;
            zr[4 * q + 2] = v.z; zr[4 * q + 3] = v.w;
        }
    }

    float bv = NEG_BIG; int bp = P_DIM;
    #pragma unroll
    for (int b = 0; b < 4; ++b) {           // ascending batches -> ascending groups
        unsigned long long mask = __ballot(gv[b] >= thr);
        while (mask) {
            int j = __ffsll((unsigned long long)mask) - 1;
            mask &= mask - 1;               // ascending j within batch
            int g = b * 64 + j;
            int p = g * GRP + (l & 31);
            const float* cg = cnG + (size_t)g * 2048;
            float a0 = 0.f, a1 = 0.f, a2 = 0.f, a3 = 0.f;
            #pragma unroll
            for (int q = 0; q < 8; ++q) {
                a0 = fmaf(cg[(4 * q + 0) * 64 + l], zr[4 * q + 0], a0);
                a1 = fmaf(cg[(4 * q + 1) * 64 + l], zr[4 * q + 1], a1);
                a2 = fmaf(cg[(4 * q + 2) * 64 + l], zr[4 * q + 2], a2);
                a3 = fmaf(cg[(4 * q + 3) * 64 + l], zr[4 * q + 3], a3);
            }
            float s = (a0 + a1) + (a2 + a3);
            s += __shfl_xor(s, 32, 64);     // combine halves: full dot in both lanes
            if (s > bv || (s == bv && p < bp)) { bv = s; bp = p; }
        }
    }
    #pragma unroll
    for (int o = 32; o; o >>= 1) {
        float ov = __shfl_xor(bv, o, 64);
        int   op = __shfl_xor(bp, o, 64);
        if (ov > bv || (ov == bv && op < bp)) { bv = ov; bp = op; }
    }
    if (l == 0) { idx_i[m] = bp; idx_f[m] = (float)bp; }

    // fused loss partial: sum (zn - cn[bp])^2 over the row (bp wave-uniform)
    {
        const float4* cp = (const float4*)(cn + (size_t)bp * C_DIM + (l >> 5) * 32);
        float d2 = 0.f;
        #pragma unroll
        for (int q = 0; q < 8; ++q) {
            float4 w = cp[q];
            float dx = zr[4 * q + 0] - w.x; d2 = fmaf(dx, dx, d2);
            float dy = zr[4 * q + 1] - w.y; d2 = fmaf(dy, dy, d2);
            float dz = zr[4 * q + 2] - w.z; d2 = fmaf(dz, dz, d2);
            float dw = zr[4 * q + 3] - w.w; d2 = fmaf(dw, dw, d2);
        }
        d2 += __shfl_xor(d2, 32, 64);
        if (l == 0) lossp[m] = d2;
    }
}

// ---------------- Kernel D (merged with loss-final): out + loss reduce ----------
#define D_ROWS 128
#define D_BLKS (M_TOT / D_ROWS * (F_DIM / 64))      // 1536
__global__ void k_out(const int* __restrict__ idx, const float* __restrict__ cn,
                      const float* __restrict__ wT, float* __restrict__ out,
                      const float* __restrict__ lossp, float* __restrict__ loss_out) {
    __shared__ float sh[256];
    int bx = blockIdx.x;
    if (bx >= D_BLKS) {
        float s = 0.f;
        for (int i = threadIdx.x; i < M_TOT; i += 256) s += lossp[i];
        sh[threadIdx.x] = s;
        __syncthreads();
        for (int o = 128; o; o >>= 1) {
            if (threadIdx.x < o) sh[threadIdx.x] += sh[threadIdx.x + o];
            __syncthreads();
        }
        if (threadIdx.x == 0)
            loss_out[0] = 1.25f * sh[0] / (float)(M_TOT * C_DIM);
        return;
    }

    int wv = threadIdx.x >> 6, lane = threadIdx.x & 63;
    int f  = (bx >> 7) * 64 + lane;     // bx/128 in 0..11
    int m0 = (bx & 127) * D_ROWS + wv * 32;

    float wcol[64];
    #pragma unroll
    for (int c = 0; c < 64; ++c) wcol[c] = wT[(size_t)c * F_DIM + f];

    #pragma unroll 4
    for (int r = 0; r < 32; ++r) {
        int m = __builtin_amdgcn_readfirstlane(m0 + r);
        const float4* cp = (const float4*)(cn + (size_t)idx[m] * C_DIM);
        float a0 = 0.f, a1 = 0.f, a2 = 0.f, a3 = 0.f;
        #pragma unroll
        for (int j = 0; j < 16; ++j) {
            float4 cv = cp[j];
            a0 = fmaf(cv.x, wcol[4 * j + 0], a0);
            a1 = fmaf(cv.y, wcol[4 * j + 1], a1);
            a2 = fmaf(cv.z, wcol[4 * j + 2], a2);
            a3 = fmaf(cv.w, wcol[4 * j + 3], a3);
        }
        out[(size_t)m * F_DIM + f] = (a0 + a1) + (a2 + a3);
    }
}

extern "C" void kernel_launch(void* const* d_in, const int* in_sizes, int n_in,
                              void* d_out, int out_size, void* d_ws, size_t ws_size,
                              hipStream_t stream) {
    const float* z     = (const float*)d_in[0];
    const float* w_in  = (const float*)d_in[1];
    const float* w_out = (const float*)d_in[2];
    const float* cb    = (const float*)d_in[3];

    float* out    = (float*)d_out;
    float* lossO  = out + (size_t)M_TOT * F_DIM;
    float* idxO   = lossO + 1;
    // gmaxT (16.8 MB, [M_TOT][NGRP]) lives in the d_out 'out' region: written by
    // k_simmax, read by k_pick, then fully overwritten by k_out (stream-ordered).
    float* gmaxT  = out;

    float* ws    = (float*)d_ws;                          // total ~11.4 MB
    float* cn    = ws;                                    // 524288 f   (2 MB)
    float* zn    = cn + (size_t)P_DIM * C_DIM;            // 1048576 f  (4 MB)
    float* wT    = zn + (size_t)M_TOT * C_DIM;            // 49152 f
    float* lossp = wT + (size_t)C_DIM * F_DIM;            // 16384 f
    int*   idxi  = (int*)(lossp + M_TOT);                 // 16384 i
    float* cnG   = (float*)(idxi + M_TOT);                // 524288 f   (2 MB)
    ushort_t* zhF = (ushort_t*)(cnG + (size_t)P_DIM * C_DIM); // 1048576 us (2 MB)
    ushort_t* chF = zhF + (size_t)M_TOT * C_DIM;          // 524288 us  (1 MB)

    int projGrid = PROJ_BLKS + P_DIM / 4 + (C_DIM * F_DIM) / 256;   // 512+2048+192
    k_proj<<<projGrid, 256, 0, stream>>>(z, w_in, zn, zhF, cb, cn, chF, cnG, w_out, wT);

    dim3 gC(M_TOT / 256, NCH);
    k_simmax<<<gC, 256, 0, stream>>>(zhF, chF, gmaxT);
    k_pick<<<M_TOT / 4, 256, 0, stream>>>(gmaxT, zn, cn, cnG, idxi, idxO, lossp);

    k_out<<<D_BLKS + 1, 256, 0, stream>>>(idxi, cn, wT, out, lossp, lossO);
}